// Round 5
// baseline (1566.962 us; speedup 1.0000x reference)
//
#include <hip/hip_runtime.h>

typedef __attribute__((ext_vector_type(8))) __bf16 bf16x8;
typedef __attribute__((ext_vector_type(8))) unsigned short ushort8;
typedef __attribute__((ext_vector_type(4))) float floatx4;

#define NB 2
#define SEQ 2048
#define DIM 384
#define NH 8
#define HD 48
#define HDP 64
#define FF 1536
#define NLAYER 8
#define ATT_SCALE 0.14433756729740643f  // 1/sqrt(48)

__device__ __forceinline__ unsigned short f2bf(float f) {
  unsigned u = __builtin_bit_cast(unsigned, f);
  u += 0x7fffu + ((u >> 16) & 1u);
  return (unsigned short)(u >> 16);
}
__device__ __forceinline__ float bf2f(unsigned short h) {
  unsigned u = ((unsigned)h) << 16;
  return __builtin_bit_cast(float, u);
}
__device__ __forceinline__ bf16x8 ldb8(const unsigned short* p) {
  return __builtin_bit_cast(bf16x8, *(const ushort8*)p);
}
__device__ __forceinline__ void gl2lds16(const unsigned short* g, unsigned short* l) {
  __builtin_amdgcn_global_load_lds((const __attribute__((address_space(1))) unsigned int*)g,
                                   (__attribute__((address_space(3))) unsigned int*)l, 16, 0, 0);
}
#define MFMA(a, b, c) __builtin_amdgcn_mfma_f32_16x16x32_bf16(a, b, c, 0, 0, 0)

// ---------------- weight transpose+convert: W (K x N) fp32 -> Wt (N x K) bf16 ----
__global__ __launch_bounds__(256) void wtrans_kernel(const float* __restrict__ W,
                                                     unsigned short* __restrict__ Wt,
                                                     int K, int N,
                                                     size_t sstride, size_t dstride) {
  __shared__ unsigned short tile[32][33];
  const float* Wl = W + (size_t)blockIdx.z * sstride;
  unsigned short* Wtl = Wt + (size_t)blockIdx.z * dstride;
  int n0 = blockIdx.x * 32, k0 = blockIdx.y * 32;
  int tx = threadIdx.x, ty = threadIdx.y;  // block (32,8)
  for (int i = ty; i < 32; i += 8)
    tile[i][tx] = f2bf(Wl[(size_t)(k0 + i) * N + n0 + tx]);
  __syncthreads();
  for (int i = ty; i < 32; i += 8)
    Wtl[(size_t)(n0 + i) * K + k0 + tx] = tile[tx][i];
}

// ---------------- qkv bias concat [8][1152] ----------------
__global__ void biascat_kernel(const float* __restrict__ bq, const float* __restrict__ bk,
                               const float* __restrict__ bv, float* __restrict__ out) {
  int idx = blockIdx.x * 256 + threadIdx.x;
  if (idx >= NLAYER * 1152) return;
  int z = idx / 1152, j = idx % 1152;
  float v = (j < 384) ? bq[z * 384 + j] : (j < 768) ? bk[z * 384 + j - 384] : bv[z * 384 + j - 768];
  out[idx] = v;
}

// ---------------- rope tables ----------------
__global__ void ropetab_kernel(float* __restrict__ cosT, float* __restrict__ sinT) {
  int idx = blockIdx.x * 256 + threadIdx.x;
  if (idx >= SEQ * HD) return;
  int l = idx / HD, d = idx % HD;
  int j = d % 24;
  float inv = powf(10000.0f, -(float)j / 24.0f);
  float pos;
  if (j < 6) pos = (float)(l >> 8);
  else if (j < 15) pos = (float)((l >> 4) & 15);
  else pos = (float)(l & 15);
  float f = pos * inv;
  cosT[idx] = cosf(f);
  sinT[idx] = sinf(f);
}

// ---------------- gather (ids_restore) + input RMS -> fp32 stream x ----------------
__global__ __launch_bounds__(256) void gatherrms_kernel(const float* __restrict__ vis,
                                                        const int* __restrict__ ids,
                                                        const float* __restrict__ mask_token,
                                                        const float* __restrict__ w,
                                                        float* __restrict__ x) {
  int wv = threadIdx.x >> 6, lane = threadIdx.x & 63;
  int row = blockIdx.x * 4 + wv;  // b*2048 + l
  int b = row >> 11;
  int src = ids[row];
  const float* p = (src < 512) ? (vis + ((size_t)b * 512 + src) * DIM) : mask_token;
  float v[6];
  float ss = 0.f;
#pragma unroll
  for (int j = 0; j < 6; j++) { v[j] = p[lane + 64 * j]; ss += v[j] * v[j]; }
#pragma unroll
  for (int m = 32; m; m >>= 1) ss += __shfl_xor(ss, m);
  float s = rsqrtf(ss * (1.0f / DIM) + 1e-6f);
#pragma unroll
  for (int j = 0; j < 6; j++)
    x[(size_t)row * DIM + lane + 64 * j] = v[j] * s * w[lane + 64 * j];
}

// ---------------- RMS (fp32 in) -> bf16 out ----------------
__global__ __launch_bounds__(256) void rmsbf_kernel(const float* __restrict__ x,
                                                    const float* __restrict__ w,
                                                    unsigned short* __restrict__ out) {
  int wv = threadIdx.x >> 6, lane = threadIdx.x & 63;
  int row = blockIdx.x * 4 + wv;
  const float* xr = x + (size_t)row * DIM;
  float v[6];
  float ss = 0.f;
#pragma unroll
  for (int j = 0; j < 6; j++) { v[j] = xr[lane + 64 * j]; ss += v[j] * v[j]; }
#pragma unroll
  for (int m = 32; m; m >>= 1) ss += __shfl_xor(ss, m);
  float s = rsqrtf(ss * (1.0f / DIM) + 1e-6f);
#pragma unroll
  for (int j = 0; j < 6; j++)
    out[(size_t)row * DIM + lane + 64 * j] = f2bf(v[j] * s * w[lane + 64 * j]);
}

// ============ epilogue writer shared by both GEMMs ============
__device__ __forceinline__ void gemm_store(int mode, int rg, int cg, float v, int N,
                                           unsigned short* outb, unsigned short* outb2,
                                           unsigned short* outv, float* outf) {
  if (mode == 2) {
    outf[(size_t)rg * N + cg] += v;
  } else if (mode == 3) {
    float g = v * 0.5f * (1.0f + erff(v * 0.70710678f));
    outb[(size_t)rg * N + cg] = f2bf(g);
  } else {  // mode 4: qkv split
    if (cg < 384) {
      outb[(size_t)rg * 384 + cg] = f2bf(v);
    } else if (cg < 768) {
      outb2[(size_t)rg * 384 + cg - 384] = f2bf(v);
    } else {
      int j = cg - 768;
      int h = j / HD, hd = j % HD;
      int b = rg >> 11, l = rg & 2047;
      outv[(((size_t)b * NH + h) * HDP + hd) * SEQ + l] = f2bf(v);
    }
  }
}

// ---------------- 64x64-tile GEMM (LDS staged via VGPR) ----------------
__global__ __launch_bounds__(256) void gemm_kernel(const unsigned short* __restrict__ A,
                                                   const unsigned short* __restrict__ Wt,
                                                   const float* __restrict__ bias,
                                                   int M, int N, int K, int mode,
                                                   unsigned short* __restrict__ outb,
                                                   unsigned short* __restrict__ outb2,
                                                   unsigned short* __restrict__ outv,
                                                   float* __restrict__ outf) {
  __shared__ __align__(16) unsigned short As[64][40];
  __shared__ __align__(16) unsigned short Bs[64][40];
  int tid = threadIdx.x;
  int wv = tid >> 6, lane = tid & 63;
  int wm = wv >> 1, wn = wv & 1;
  int row0 = blockIdx.x * 64, col0 = blockIdx.y * 64;
  int q = lane >> 4, c = lane & 15;
  floatx4 acc[2][2] = {};
  int srow = tid >> 2, sk = (tid & 3) * 8;
  const unsigned short* Ap = A + (size_t)(row0 + srow) * K + sk;
  const unsigned short* Bp = Wt + (size_t)(col0 + srow) * K + sk;
  for (int k0 = 0; k0 < K; k0 += 32) {
    *(ushort8*)(&As[srow][sk]) = *(const ushort8*)(Ap + k0);
    *(ushort8*)(&Bs[srow][sk]) = *(const ushort8*)(Bp + k0);
    __syncthreads();
    bf16x8 a0 = ldb8(&As[wm * 32 + c][q * 8]);
    bf16x8 a1 = ldb8(&As[wm * 32 + 16 + c][q * 8]);
    bf16x8 b0 = ldb8(&Bs[wn * 32 + c][q * 8]);
    bf16x8 b1 = ldb8(&Bs[wn * 32 + 16 + c][q * 8]);
    acc[0][0] = MFMA(a0, b0, acc[0][0]);
    acc[0][1] = MFMA(a0, b1, acc[0][1]);
    acc[1][0] = MFMA(a1, b0, acc[1][0]);
    acc[1][1] = MFMA(a1, b1, acc[1][1]);
    __syncthreads();
  }
#pragma unroll
  for (int tm = 0; tm < 2; tm++)
#pragma unroll
    for (int tn = 0; tn < 2; tn++)
#pragma unroll
      for (int r = 0; r < 4; r++) {
        int rg = row0 + wm * 32 + tm * 16 + q * 4 + r;
        int cg = col0 + wn * 32 + tn * 16 + c;
        gemm_store(mode, rg, cg, acc[tm][tn][r] + bias[cg], N, outb, outb2, outv, outf);
      }
}

// ---------------- 128x128-tile GEMM, global_load_lds width-16 staging (m97 structure) ------
__global__ __launch_bounds__(256) void gemm128_kernel(const unsigned short* __restrict__ A,
                                                      const unsigned short* __restrict__ Wt,
                                                      const float* __restrict__ bias,
                                                      int M, int N, int K, int mode,
                                                      unsigned short* __restrict__ outb,
                                                      unsigned short* __restrict__ outb2,
                                                      unsigned short* __restrict__ outv,
                                                      float* __restrict__ outf) {
  __shared__ __align__(16) unsigned short As[128 * 32];
  __shared__ __align__(16) unsigned short Bs[128 * 32];
  int tid = threadIdx.x;
  int wv = tid >> 6, lane = tid & 63;
  int q = lane >> 4, c = lane & 15;
  int wm = wv >> 1, wn = wv & 1;
  int row0 = blockIdx.x * 128, col0 = blockIdx.y * 128;
  floatx4 acc[4][4] = {};
  int sr = tid >> 2, sk = (tid & 3) * 8;
  const unsigned short* Ag = A + (size_t)(row0 + sr) * K + sk;
  const unsigned short* Bg = Wt + (size_t)(col0 + sr) * K + sk;
  unsigned short* Asl = As + tid * 8;
  unsigned short* Bsl = Bs + tid * 8;
  for (int k0 = 0; k0 < K; k0 += 32) {
    gl2lds16(Ag + k0, Asl);
    gl2lds16(Ag + (size_t)64 * K + k0, Asl + 2048);
    gl2lds16(Bg + k0, Bsl);
    gl2lds16(Bg + (size_t)64 * K + k0, Bsl + 2048);
    __syncthreads();
    bf16x8 af[4], bfr[4];
#pragma unroll
    for (int mt = 0; mt < 4; mt++) af[mt] = ldb8(&As[(wm * 64 + mt * 16 + c) * 32 + q * 8]);
#pragma unroll
    for (int nt = 0; nt < 4; nt++) bfr[nt] = ldb8(&Bs[(wn * 64 + nt * 16 + c) * 32 + q * 8]);
#pragma unroll
    for (int mt = 0; mt < 4; mt++)
#pragma unroll
      for (int nt = 0; nt < 4; nt++) acc[mt][nt] = MFMA(af[mt], bfr[nt], acc[mt][nt]);
    __syncthreads();
  }
#pragma unroll
  for (int mt = 0; mt < 4; mt++)
#pragma unroll
    for (int nt = 0; nt < 4; nt++)
#pragma unroll
      for (int r = 0; r < 4; r++) {
        int rg = row0 + wm * 64 + mt * 16 + q * 4 + r;
        int cg = col0 + wn * 64 + nt * 16 + c;
        gemm_store(mode, rg, cg, acc[mt][nt][r] + bias[cg], N, outb, outb2, outv, outf);
      }
}

// ---------------- rope: qpre/kpre (bf16 row-major) -> q/k [b][h][l][64]; q scaled ----------
__global__ __launch_bounds__(384) void rope_kernel(const unsigned short* __restrict__ qpre,
                                                   const unsigned short* __restrict__ kpre,
                                                   const float* __restrict__ cosT,
                                                   const float* __restrict__ sinT,
                                                   unsigned short* __restrict__ qdst,
                                                   unsigned short* __restrict__ kdst) {
  int row = blockIdx.x;  // b*2048 + l
  int b = row >> 11, l = row & 2047;
  int t = threadIdx.x;
  const unsigned short* src = (t >= 192) ? kpre : qpre;
  unsigned short* dst = (t >= 192) ? kdst : qdst;
  float sc = (t >= 192) ? 1.0f : ATT_SCALE;  // fold 1/sqrt(hd) into q
  int pp = t % 192;
  int h = pp / 24, d = pp % 24;
  float x1 = bf2f(src[(size_t)row * DIM + h * HD + d]);
  float x2 = bf2f(src[(size_t)row * DIM + h * HD + d + 24]);
  float cs = cosT[l * HD + d], sn = sinT[l * HD + d];
  size_t base = (((size_t)b * NH + h) * SEQ + l) * HDP;
  dst[base + d] = f2bf((x1 * cs - x2 * sn) * sc);
  dst[base + d + 24] = f2bf((x2 * cs + x1 * sn) * sc);
}

// ---------------- flash attention v5: S^T orientation, no K/V LDS, no barriers ------------
// Score: S^T = MFMA(A=K, B=Q)  -> lane (q,c): S[qrow=c][key=t*16+q*4+r]
// Softmax stats per-lane (qrow=c), O accumulated transposed: O^T[d][qrow=c].
// P packed via v_perm (bf16-trunc) -> conflict-free ds_write_b64, read back as B-frag.
// K and V A-fragments read straight from global (L2-served, XCD-swizzled).
__global__ __launch_bounds__(256) void fattn_kernel(const unsigned short* __restrict__ qb,
                                                    const unsigned short* __restrict__ kb,
                                                    const unsigned short* __restrict__ vt,
                                                    unsigned short* __restrict__ obuf) {
  __shared__ __align__(16) unsigned short Pt[4][16][72];
  int tid = threadIdx.x;
  int wv = tid >> 6, lane = tid & 63;
  int q = lane >> 4, c = lane & 15;
  int i = blockIdx.x;
  int bh = 2 * (i & 7) + ((i >> 3) & 1);  // XCD swizzle: 2 heads per XCD
  int q0 = (i >> 4) * 64;
  int kstart = q0 & ~255;  // frame-aligned reverse-causal mask
  int myrow = q0 + wv * 16;
  const unsigned short* qbase = qb + (size_t)bh * SEQ * HDP;
  const unsigned short* kbase = kb + (size_t)bh * SEQ * HDP;
  const unsigned short* vbase = vt + (size_t)bh * HDP * SEQ;
  // Q B-frag: B[n=qrow=c][k=d=q*8+j]
  bf16x8 a0 = ldb8(qbase + (size_t)(myrow + c) * HDP + q * 8);
  bf16x8 a1 = ldb8(qbase + (size_t)(myrow + c) * HDP + 32 + q * 8);
  floatx4 O[3] = {};  // O^T[d = f*16+q*4+r][qrow=c]
  float m = -3e38f, l = 0.f;
  unsigned short* myPt = &Pt[wv][0][0];
  for (int k0 = kstart; k0 < SEQ; k0 += 64) {
    // scores: 4 key-tiles of 16
    floatx4 S[4];
#pragma unroll
    for (int t = 0; t < 4; t++) {
      const unsigned short* krow = kbase + (size_t)(k0 + t * 16 + c) * HDP;
      bf16x8 kf0 = ldb8(krow + q * 8);
      bf16x8 kf1 = ldb8(krow + 32 + q * 8);
      floatx4 z = {};
      z = MFMA(kf0, a0, z);
      S[t] = MFMA(kf1, a1, z);
    }
    // V A-frags (prefetch while softmax runs): A[m=d=f*16+c][k=key=q*8+j]
    bf16x8 vf[3][2];
#pragma unroll
    for (int f = 0; f < 3; f++) {
      const unsigned short* vrow = vbase + (size_t)(f * 16 + c) * SEQ + k0;
      vf[f][0] = ldb8(vrow + q * 8);
      vf[f][1] = ldb8(vrow + 32 + q * 8);
    }
    // per-lane online softmax over 16 local keys of qrow c
    float mx = -3e38f;
#pragma unroll
    for (int t = 0; t < 4; t++)
#pragma unroll
      for (int r = 0; r < 4; r++) mx = fmaxf(mx, S[t][r]);
    mx = fmaxf(mx, __shfl_xor(mx, 16));
    mx = fmaxf(mx, __shfl_xor(mx, 32));
    float nm = fmaxf(m, mx);
    float alpha = __expf(m - nm);
    m = nm;
    l *= alpha;
#pragma unroll
    for (int t = 0; t < 4; t++) {
      float e0 = __expf(S[t][0] - m), e1 = __expf(S[t][1] - m);
      float e2 = __expf(S[t][2] - m), e3 = __expf(S[t][3] - m);
      l += (e0 + e1) + (e2 + e3);
      unsigned dw0 = __builtin_amdgcn_perm(__builtin_bit_cast(unsigned, e1),
                                           __builtin_bit_cast(unsigned, e0), 0x07060302u);
      unsigned dw1 = __builtin_amdgcn_perm(__builtin_bit_cast(unsigned, e3),
                                           __builtin_bit_cast(unsigned, e2), 0x07060302u);
      uint2 dw = {dw0, dw1};
      *(uint2*)(myPt + c * 72 + t * 16 + q * 4) = dw;  // keys t*16+q*4.. of qrow c
    }
#pragma unroll
    for (int f = 0; f < 3; f++)
#pragma unroll
      for (int r = 0; r < 4; r++) O[f][r] *= alpha;
    // P B-frag: B[n=qrow=c][k=key=q*8+j]
    bf16x8 pb0 = ldb8(myPt + c * 72 + q * 8);
    bf16x8 pb1 = ldb8(myPt + c * 72 + 32 + q * 8);
#pragma unroll
    for (int f = 0; f < 3; f++) {
      O[f] = MFMA(vf[f][0], pb0, O[f]);
      O[f] = MFMA(vf[f][1], pb1, O[f]);
    }
  }
  l += __shfl_xor(l, 16);
  l += __shfl_xor(l, 32);
  float linv = 1.0f / l;
  int b = bh >> 3, h = bh & 7;
  size_t orow = ((size_t)b * SEQ + myrow + c) * DIM + h * HD;
#pragma unroll
  for (int f = 0; f < 3; f++)
#pragma unroll
    for (int r = 0; r < 4; r++)
      obuf[orow + f * 16 + q * 4 + r] = f2bf(O[f][r] * linv);
}

// ---------------- stable argsort(-mask) ranks via block scan ----------------
__global__ __launch_bounds__(256) void rank_kernel(const int* __restrict__ mask,
                                                   int* __restrict__ dest) {
  __shared__ int wsum[4];
  int b = blockIdx.x, t = threadIdx.x;
  int lane = t & 63, wv = t >> 6;
  const int* mb = mask + b * SEQ;
  int base = t * 8;
  int v[8];
  int s = 0;
#pragma unroll
  for (int j = 0; j < 8; j++) { v[j] = mb[base + j]; s += v[j]; }
  int incl = s;
  for (int off = 1; off < 64; off <<= 1) {
    int n = __shfl_up(incl, off);
    if (lane >= off) incl += n;
  }
  if (lane == 63) wsum[wv] = incl;
  __syncthreads();
  int P = incl - s;
  for (int w = 0; w < wv; w++) P += wsum[w];
  int run = 0;
#pragma unroll
  for (int j = 0; j < 8; j++) {
    int ones = P + run;
    int l = base + j;
    dest[b * SEQ + l] = v[j] ? ones : 512 + (l - ones);
    run += v[j];
  }
}

// ---------------- write decoded_full + scattered visible/masked ----------------
__global__ __launch_bounds__(256) void output_kernel(const float* __restrict__ x,
                                                     const int* __restrict__ dest,
                                                     float* __restrict__ out) {
  int idx = blockIdx.x * 256 + threadIdx.x;  // NB*SEQ*96
  int row = idx / 96, c = idx % 96;
  float4 v = ((const float4*)(x + (size_t)row * DIM))[c];
  ((float4*)(out + (size_t)row * DIM))[c] = v;
  int b = row >> 11;
  int d = dest[row];
  size_t base = (size_t)NB * SEQ * DIM;
  size_t o;
  if (d < 512) o = base + ((size_t)b * 512 + d) * DIM;
  else o = base + (size_t)NB * 512 * DIM + ((size_t)b * 1536 + (d - 512)) * DIM;
  ((float4*)(out + o))[c] = v;
}

extern "C" void kernel_launch(void* const* d_in, const int* in_sizes, int n_in,
                              void* d_out, int out_size, void* d_ws, size_t ws_size,
                              hipStream_t stream) {
  const float* vis = (const float*)d_in[0];
  const int* ids = (const int*)d_in[1];
  const int* mask = (const int*)d_in[2];
  const float* mask_token = (const float*)d_in[6];
  const float* ln_in_w = (const float*)d_in[7];
  const float* ln1_w = (const float*)d_in[8];
  const float* ln2_w = (const float*)d_in[9];
  const float* Wq = (const float*)d_in[10];
  const float* bq = (const float*)d_in[11];
  const float* Wk = (const float*)d_in[12];
  const float* bk = (const float*)d_in[13];
  const float* Wv = (const float*)d_in[14];
  const float* bv = (const float*)d_in[15];
  const float* Wo = (const float*)d_in[16];
  const float* bo = (const float*)d_in[17];
  const float* W1 = (const float*)d_in[18];
  const float* b1 = (const float*)d_in[19];
  const float* W2 = (const float*)d_in[20];
  const float* b2 = (const float*)d_in[21];

  char* p = (char*)d_ws;
  size_t off = 0;
  auto alloc = [&](size_t n) -> void* {
    off = (off + 255) & ~(size_t)255;
    void* r = p + off;
    off += n;
    return r;
  };
  unsigned short* wqkvT = (unsigned short*)alloc((size_t)NLAYER * 1152 * DIM * 2);
  unsigned short* woT = (unsigned short*)alloc((size_t)NLAYER * DIM * DIM * 2);
  unsigned short* w1T = (unsigned short*)alloc((size_t)NLAYER * DIM * FF * 2);
  unsigned short* w2T = (unsigned short*)alloc((size_t)NLAYER * DIM * FF * 2);
  float* bqkv = (float*)alloc((size_t)NLAYER * 1152 * 4);
  float* cosT = (float*)alloc((size_t)SEQ * HD * 4);
  float* sinT = (float*)alloc((size_t)SEQ * HD * 4);
  float* x = (float*)alloc((size_t)NB * SEQ * DIM * 4);
  unsigned short* hdn = (unsigned short*)alloc((size_t)NB * SEQ * DIM * 2);
  unsigned short* qpre = (unsigned short*)alloc((size_t)NB * SEQ * DIM * 2);
  unsigned short* kpre = (unsigned short*)alloc((size_t)NB * SEQ * DIM * 2);
  unsigned short* qb = (unsigned short*)alloc((size_t)NB * NH * SEQ * HDP * 2);
  unsigned short* kb = (unsigned short*)alloc((size_t)NB * NH * SEQ * HDP * 2);
  unsigned short* vtb = (unsigned short*)alloc((size_t)NB * NH * SEQ * HDP * 2);
  unsigned short* obuf = (unsigned short*)alloc((size_t)NB * SEQ * DIM * 2);
  unsigned short* a1 = (unsigned short*)alloc((size_t)NB * SEQ * FF * 2);
  int* dest = (int*)alloc((size_t)NB * SEQ * 4);

  // zero head-dim pad [48,64): q/k pads are contracted over by score MFMAs.
  hipMemsetAsync(qb, 0, (size_t)NB * NH * SEQ * HDP * 2, stream);
  hipMemsetAsync(kb, 0, (size_t)NB * NH * SEQ * HDP * 2, stream);

  dim3 tb(32, 8);
  wtrans_kernel<<<dim3(12, 12, 8), tb, 0, stream>>>(Wq, wqkvT, 384, 384, 147456, 442368);
  wtrans_kernel<<<dim3(12, 12, 8), tb, 0, stream>>>(Wk, wqkvT + 147456, 384, 384, 147456, 442368);
  wtrans_kernel<<<dim3(12, 12, 8), tb, 0, stream>>>(Wv, wqkvT + 294912, 384, 384, 147456, 442368);
  wtrans_kernel<<<dim3(12, 12, 8), tb, 0, stream>>>(Wo, woT, 384, 384, 147456, 147456);
  wtrans_kernel<<<dim3(48, 12, 8), tb, 0, stream>>>(W1, w1T, 384, 1536, 589824, 589824);
  wtrans_kernel<<<dim3(12, 48, 8), tb, 0, stream>>>(W2, w2T, 1536, 384, 589824, 589824);
  biascat_kernel<<<(NLAYER * 1152 + 255) / 256, 256, 0, stream>>>(bq, bk, bv, bqkv);
  ropetab_kernel<<<(SEQ * HD + 255) / 256, 256, 0, stream>>>(cosT, sinT);
  gatherrms_kernel<<<NB * SEQ / 4, 256, 0, stream>>>(vis, ids, mask_token, ln_in_w, x);

  for (int i = 0; i < NLAYER; i++) {
    size_t wo = (size_t)i * DIM * DIM;
    size_t wf = (size_t)i * DIM * FF;
    rmsbf_kernel<<<NB * SEQ / 4, 256, 0, stream>>>(x, ln1_w + i * DIM, hdn);
    gemm128_kernel<<<dim3(32, 9), 256, 0, stream>>>(hdn, wqkvT + (size_t)i * 442368, bqkv + i * 1152,
                                                    NB * SEQ, 1152, DIM, 4, qpre, kpre, vtb, nullptr);
    rope_kernel<<<NB * SEQ, 384, 0, stream>>>(qpre, kpre, cosT, sinT, qb, kb);
    fattn_kernel<<<512, 256, 0, stream>>>(qb, kb, vtb, obuf);
    gemm_kernel<<<dim3(64, 6), 256, 0, stream>>>(obuf, woT + wo, bo + i * DIM, NB * SEQ, DIM, DIM, 2,
                                                 nullptr, nullptr, nullptr, x);
    rmsbf_kernel<<<NB * SEQ / 4, 256, 0, stream>>>(x, ln2_w + i * DIM, hdn);
    gemm128_kernel<<<dim3(32, 12), 256, 0, stream>>>(hdn, w1T + wf, b1 + i * FF, NB * SEQ, FF, DIM, 3,
                                                     a1, nullptr, nullptr, nullptr);
    gemm_kernel<<<dim3(64, 6), 256, 0, stream>>>(a1, w2T + wf, b2 + i * DIM, NB * SEQ, DIM, FF, 2,
                                                 nullptr, nullptr, nullptr, x);
  }
  rank_kernel<<<NB, 256, 0, stream>>>(mask, dest);
  output_kernel<<<NB * SEQ * 96 / 256, 256, 0, stream>>>(x, dest, (float*)d_out);
}

// Round 6
// 1148.772 us; speedup vs baseline: 1.3640x; 1.3640x over previous
//
#include <hip/hip_runtime.h>

typedef __attribute__((ext_vector_type(8))) __bf16 bf16x8;
typedef __attribute__((ext_vector_type(8))) unsigned short ushort8;
typedef __attribute__((ext_vector_type(4))) float floatx4;

#define NB 2
#define SEQ 2048
#define DIM 384
#define NH 8
#define HD 48
#define HDP 64
#define FF 1536
#define NLAYER 8
#define ATT_SCALE 0.14433756729740643f  // 1/sqrt(48)

__device__ __forceinline__ unsigned short f2bf(float f) {
  unsigned u = __builtin_bit_cast(unsigned, f);
  u += 0x7fffu + ((u >> 16) & 1u);
  return (unsigned short)(u >> 16);
}
__device__ __forceinline__ float bf2f(unsigned short h) {
  unsigned u = ((unsigned)h) << 16;
  return __builtin_bit_cast(float, u);
}
__device__ __forceinline__ bf16x8 ldb8(const unsigned short* p) {
  return __builtin_bit_cast(bf16x8, *(const ushort8*)p);
}
__device__ __forceinline__ void gl2lds16(const unsigned short* g, unsigned short* l) {
  __builtin_amdgcn_global_load_lds((const __attribute__((address_space(1))) unsigned int*)g,
                                   (__attribute__((address_space(3))) unsigned int*)l, 16, 0, 0);
}
#define MFMA(a, b, c) __builtin_amdgcn_mfma_f32_16x16x32_bf16(a, b, c, 0, 0, 0)

// ---------------- weight transpose+convert: W (K x N) fp32 -> Wt (N x K) bf16 ----
__global__ __launch_bounds__(256) void wtrans_kernel(const float* __restrict__ W,
                                                     unsigned short* __restrict__ Wt,
                                                     int K, int N,
                                                     size_t sstride, size_t dstride) {
  __shared__ unsigned short tile[32][33];
  const float* Wl = W + (size_t)blockIdx.z * sstride;
  unsigned short* Wtl = Wt + (size_t)blockIdx.z * dstride;
  int n0 = blockIdx.x * 32, k0 = blockIdx.y * 32;
  int tx = threadIdx.x, ty = threadIdx.y;  // block (32,8)
  for (int i = ty; i < 32; i += 8)
    tile[i][tx] = f2bf(Wl[(size_t)(k0 + i) * N + n0 + tx]);
  __syncthreads();
  for (int i = ty; i < 32; i += 8)
    Wtl[(size_t)(n0 + i) * K + k0 + tx] = tile[tx][i];
}

// ---------------- qkv bias concat [8][1152] ----------------
__global__ void biascat_kernel(const float* __restrict__ bq, const float* __restrict__ bk,
                               const float* __restrict__ bv, float* __restrict__ out) {
  int idx = blockIdx.x * 256 + threadIdx.x;
  if (idx >= NLAYER * 1152) return;
  int z = idx / 1152, j = idx % 1152;
  float v = (j < 384) ? bq[z * 384 + j] : (j < 768) ? bk[z * 384 + j - 384] : bv[z * 384 + j - 768];
  out[idx] = v;
}

// ---------------- rope tables ----------------
__global__ void ropetab_kernel(float* __restrict__ cosT, float* __restrict__ sinT) {
  int idx = blockIdx.x * 256 + threadIdx.x;
  if (idx >= SEQ * HD) return;
  int l = idx / HD, d = idx % HD;
  int j = d % 24;
  float inv = powf(10000.0f, -(float)j / 24.0f);
  float pos;
  if (j < 6) pos = (float)(l >> 8);
  else if (j < 15) pos = (float)((l >> 4) & 15);
  else pos = (float)(l & 15);
  float f = pos * inv;
  cosT[idx] = cosf(f);
  sinT[idx] = sinf(f);
}

// ---------------- gather (ids_restore) + input RMS -> fp32 stream x ----------------
__global__ __launch_bounds__(256) void gatherrms_kernel(const float* __restrict__ vis,
                                                        const int* __restrict__ ids,
                                                        const float* __restrict__ mask_token,
                                                        const float* __restrict__ w,
                                                        float* __restrict__ x) {
  int wv = threadIdx.x >> 6, lane = threadIdx.x & 63;
  int row = blockIdx.x * 4 + wv;  // b*2048 + l
  int b = row >> 11;
  int src = ids[row];
  const float* p = (src < 512) ? (vis + ((size_t)b * 512 + src) * DIM) : mask_token;
  float v[6];
  float ss = 0.f;
#pragma unroll
  for (int j = 0; j < 6; j++) { v[j] = p[lane + 64 * j]; ss += v[j] * v[j]; }
#pragma unroll
  for (int m = 32; m; m >>= 1) ss += __shfl_xor(ss, m);
  float s = rsqrtf(ss * (1.0f / DIM) + 1e-6f);
#pragma unroll
  for (int j = 0; j < 6; j++)
    x[(size_t)row * DIM + lane + 64 * j] = v[j] * s * w[lane + 64 * j];
}

// ---------------- fused: x += p0+p1 (optional), then RMS -> bf16 out ----------------
__global__ __launch_bounds__(256) void rmsadd_kernel(float* __restrict__ x,
                                                     const float* __restrict__ p0,
                                                     const float* __restrict__ p1,
                                                     const float* __restrict__ w,
                                                     unsigned short* __restrict__ out,
                                                     int doadd) {
  int wv = threadIdx.x >> 6, lane = threadIdx.x & 63;
  int row = blockIdx.x * 4 + wv;
  size_t base = (size_t)row * DIM;
  float v[6];
  float ss = 0.f;
  if (doadd) {
#pragma unroll
    for (int j = 0; j < 6; j++) {
      int o = lane + 64 * j;
      v[j] = x[base + o] + p0[base + o] + p1[base + o];
      x[base + o] = v[j];
      ss += v[j] * v[j];
    }
  } else {
#pragma unroll
    for (int j = 0; j < 6; j++) { v[j] = x[base + lane + 64 * j]; ss += v[j] * v[j]; }
  }
#pragma unroll
  for (int m = 32; m; m >>= 1) ss += __shfl_xor(ss, m);
  float s = rsqrtf(ss * (1.0f / DIM) + 1e-6f);
#pragma unroll
  for (int j = 0; j < 6; j++)
    out[base + lane + 64 * j] = f2bf(v[j] * s * w[lane + 64 * j]);
}

// ---------------- unified 64x64-tile GEMM, global_load_lds staging, optional split-K ------
// mode 3: gelu -> outb bf16
// mode 4: qkv split: n<384 -> outb (q), <768 -> outb2 (k), else v -> outv[b][h][hd][l]
// mode 5: fp32 partial to (z==0 ? outf0 : outf1); bias added by z==0 only
__global__ __launch_bounds__(256) void gemm64_kernel(const unsigned short* __restrict__ A,
                                                     const unsigned short* __restrict__ Wt,
                                                     const float* __restrict__ bias,
                                                     int M, int N, int K, int mode,
                                                     unsigned short* __restrict__ outb,
                                                     unsigned short* __restrict__ outb2,
                                                     unsigned short* __restrict__ outv,
                                                     float* __restrict__ outf0,
                                                     float* __restrict__ outf1) {
  __shared__ __align__(16) unsigned short As[64 * 32];
  __shared__ __align__(16) unsigned short Bs[64 * 32];
  int tid = threadIdx.x;
  int wv = tid >> 6, lane = tid & 63;
  int wm = wv >> 1, wn = wv & 1;
  int row0 = blockIdx.x * 64, col0 = blockIdx.y * 64;
  int q = lane >> 4, c = lane & 15;
  int kchunk = K / gridDim.z;
  int kb0 = blockIdx.z * kchunk;
  floatx4 acc[2][2] = {};
  int sr = tid >> 2, sk = (tid & 3) * 8;
  const unsigned short* Ag = A + (size_t)(row0 + sr) * K + kb0 + sk;
  const unsigned short* Bg = Wt + (size_t)(col0 + sr) * K + kb0 + sk;
  unsigned short* Asl = As + tid * 8;
  unsigned short* Bsl = Bs + tid * 8;
  for (int k0 = 0; k0 < kchunk; k0 += 32) {
    gl2lds16(Ag + k0, Asl);
    gl2lds16(Bg + k0, Bsl);
    __syncthreads();
    bf16x8 a0 = ldb8(&As[(wm * 32 + c) * 32 + q * 8]);
    bf16x8 a1 = ldb8(&As[(wm * 32 + 16 + c) * 32 + q * 8]);
    bf16x8 b0 = ldb8(&Bs[(wn * 32 + c) * 32 + q * 8]);
    bf16x8 b1 = ldb8(&Bs[(wn * 32 + 16 + c) * 32 + q * 8]);
    acc[0][0] = MFMA(a0, b0, acc[0][0]);
    acc[0][1] = MFMA(a0, b1, acc[0][1]);
    acc[1][0] = MFMA(a1, b0, acc[1][0]);
    acc[1][1] = MFMA(a1, b1, acc[1][1]);
    __syncthreads();
  }
  float* outf = blockIdx.z ? outf1 : outf0;
  int addb = (blockIdx.z == 0);
#pragma unroll
  for (int tm = 0; tm < 2; tm++)
#pragma unroll
    for (int tn = 0; tn < 2; tn++)
#pragma unroll
      for (int r = 0; r < 4; r++) {
        int rg = row0 + wm * 32 + tm * 16 + q * 4 + r;
        int cg = col0 + wn * 32 + tn * 16 + c;
        float v = acc[tm][tn][r] + (addb ? bias[cg] : 0.f);
        if (mode == 3) {
          float g = v * 0.5f * (1.0f + erff(v * 0.70710678f));
          outb[(size_t)rg * N + cg] = f2bf(g);
        } else if (mode == 4) {
          if (cg < 384) {
            outb[(size_t)rg * 384 + cg] = f2bf(v);
          } else if (cg < 768) {
            outb2[(size_t)rg * 384 + cg - 384] = f2bf(v);
          } else {
            int j = cg - 768;
            int h = j / HD, hd = j % HD;
            int b = rg >> 11, l = rg & 2047;
            outv[(((size_t)b * NH + h) * HDP + hd) * SEQ + l] = f2bf(v);
          }
        } else {  // mode 5
          outf[(size_t)rg * N + cg] = v;
        }
      }
}

// ---------------- rope: qpre/kpre (bf16 row-major) -> q/k [b][h][l][64]; q scaled ----------
__global__ __launch_bounds__(384) void rope_kernel(const unsigned short* __restrict__ qpre,
                                                   const unsigned short* __restrict__ kpre,
                                                   const float* __restrict__ cosT,
                                                   const float* __restrict__ sinT,
                                                   unsigned short* __restrict__ qdst,
                                                   unsigned short* __restrict__ kdst) {
  int row = blockIdx.x;  // b*2048 + l
  int b = row >> 11, l = row & 2047;
  int t = threadIdx.x;
  const unsigned short* src = (t >= 192) ? kpre : qpre;
  unsigned short* dst = (t >= 192) ? kdst : qdst;
  float sc = (t >= 192) ? 1.0f : ATT_SCALE;  // fold 1/sqrt(hd) into q
  int pp = t % 192;
  int h = pp / 24, d = pp % 24;
  float x1 = bf2f(src[(size_t)row * DIM + h * HD + d]);
  float x2 = bf2f(src[(size_t)row * DIM + h * HD + d + 24]);
  float cs = cosT[l * HD + d], sn = sinT[l * HD + d];
  size_t base = (((size_t)b * NH + h) * SEQ + l) * HDP;
  dst[base + d] = f2bf((x1 * cs - x2 * sn) * sc);
  dst[base + d + 24] = f2bf((x2 * cs + x1 * sn) * sc);
}

// ---------------- flash attention (R4 structure): 64 q-rows/block, LDS-shared K/V ---------
__global__ __launch_bounds__(256) void fattn_kernel(const unsigned short* __restrict__ qb,
                                                    const unsigned short* __restrict__ kb,
                                                    const unsigned short* __restrict__ vt,
                                                    unsigned short* __restrict__ obuf) {
  __shared__ __align__(16) unsigned short Ks[64][72];
  __shared__ __align__(16) unsigned short Vs[48][72];
  __shared__ __align__(16) unsigned short Pt[4][16][72];
  int tid = threadIdx.x;
  int wv = tid >> 6, lane = tid & 63;
  int q = lane >> 4, c = lane & 15;
  int i = blockIdx.x;
  int bh = 2 * (i & 7) + ((i >> 3) & 1);
  int q0 = (i >> 4) * 64;
  int kstart = q0 & ~255;  // frame-aligned reverse-causal mask
  const unsigned short* qbase = qb + (size_t)bh * SEQ * HDP;
  const unsigned short* kbase = kb + (size_t)bh * SEQ * HDP;
  const unsigned short* vbase = vt + (size_t)bh * HDP * SEQ;
  int myrow = q0 + wv * 16;
  bf16x8 a0 = ldb8(qbase + (size_t)(myrow + c) * HDP + q * 8);
  bf16x8 a1 = ldb8(qbase + (size_t)(myrow + c) * HDP + 32 + q * 8);
  floatx4 O[3] = {};
  float mr[4] = {-3e38f, -3e38f, -3e38f, -3e38f};
  float lr[4] = {0.f, 0.f, 0.f, 0.f};
  int srow = tid >> 2, schunk = (tid & 3) * 16;
  for (int k0 = kstart; k0 < SEQ; k0 += 64) {
    const unsigned short* kg = kbase + (size_t)(k0 + srow) * HDP + schunk;
    *(ushort8*)(&Ks[srow][schunk]) = *(const ushort8*)kg;
    *(ushort8*)(&Ks[srow][schunk + 8]) = *(const ushort8*)(kg + 8);
    if (srow < 48) {
      const unsigned short* vg = vbase + (size_t)srow * SEQ + k0 + schunk;
      *(ushort8*)(&Vs[srow][schunk]) = *(const ushort8*)vg;
      *(ushort8*)(&Vs[srow][schunk + 8]) = *(const ushort8*)(vg + 8);
    }
    __syncthreads();
    floatx4 S[4];
#pragma unroll
    for (int t = 0; t < 4; t++) {
      bf16x8 b0 = ldb8(&Ks[t * 16 + c][q * 8]);
      bf16x8 b1 = ldb8(&Ks[t * 16 + c][32 + q * 8]);
      floatx4 z = {};
      z = MFMA(a0, b0, z);
      S[t] = MFMA(a1, b1, z);
    }
    float alpha[4];
#pragma unroll
    for (int r = 0; r < 4; r++) {
      float m0 = fmaxf(fmaxf(S[0][r], S[1][r]), fmaxf(S[2][r], S[3][r]));
#pragma unroll
      for (int msk = 1; msk < 16; msk <<= 1) m0 = fmaxf(m0, __shfl_xor(m0, msk, 16));
      float nm = fmaxf(mr[r], m0);
      alpha[r] = __expf(mr[r] - nm);
      mr[r] = nm;
      lr[r] *= alpha[r];
    }
#pragma unroll
    for (int t = 0; t < 4; t++)
#pragma unroll
      for (int r = 0; r < 4; r++) {
        float pv = __expf(S[t][r] - mr[r]);
        lr[r] += pv;
        Pt[wv][q * 4 + r][t * 16 + c] = f2bf(pv);
      }
#pragma unroll
    for (int f = 0; f < 3; f++)
#pragma unroll
      for (int r = 0; r < 4; r++) O[f][r] *= alpha[r];
    bf16x8 pa0 = ldb8(&Pt[wv][c][q * 8]);
    bf16x8 pa1 = ldb8(&Pt[wv][c][32 + q * 8]);
#pragma unroll
    for (int f = 0; f < 3; f++) {
      bf16x8 v0 = ldb8(&Vs[f * 16 + c][q * 8]);
      bf16x8 v1 = ldb8(&Vs[f * 16 + c][32 + q * 8]);
      O[f] = MFMA(pa0, v0, O[f]);
      O[f] = MFMA(pa1, v1, O[f]);
    }
    __syncthreads();
  }
#pragma unroll
  for (int r = 0; r < 4; r++) {
#pragma unroll
    for (int msk = 1; msk < 16; msk <<= 1) lr[r] += __shfl_xor(lr[r], msk, 16);
    lr[r] = 1.0f / lr[r];
  }
  int b = bh >> 3, h = bh & 7;
#pragma unroll
  for (int f = 0; f < 3; f++)
#pragma unroll
    for (int r = 0; r < 4; r++)
      obuf[((size_t)b * SEQ + myrow + q * 4 + r) * DIM + h * HD + f * 16 + c] =
          f2bf(O[f][r] * lr[r]);
}

// ---------------- stable argsort(-mask) ranks via block scan ----------------
__global__ __launch_bounds__(256) void rank_kernel(const int* __restrict__ mask,
                                                   int* __restrict__ dest) {
  __shared__ int wsum[4];
  int b = blockIdx.x, t = threadIdx.x;
  int lane = t & 63, wv = t >> 6;
  const int* mb = mask + b * SEQ;
  int base = t * 8;
  int v[8];
  int s = 0;
#pragma unroll
  for (int j = 0; j < 8; j++) { v[j] = mb[base + j]; s += v[j]; }
  int incl = s;
  for (int off = 1; off < 64; off <<= 1) {
    int n = __shfl_up(incl, off);
    if (lane >= off) incl += n;
  }
  if (lane == 63) wsum[wv] = incl;
  __syncthreads();
  int P = incl - s;
  for (int w = 0; w < wv; w++) P += wsum[w];
  int run = 0;
#pragma unroll
  for (int j = 0; j < 8; j++) {
    int ones = P + run;
    int l = base + j;
    dest[b * SEQ + l] = v[j] ? ones : 512 + (l - ones);
    run += v[j];
  }
}

// ---------------- final: x+p0+p1 -> decoded_full + scattered visible/masked ----------------
__global__ __launch_bounds__(256) void output_kernel(const float* __restrict__ x,
                                                     const float* __restrict__ p0,
                                                     const float* __restrict__ p1,
                                                     const int* __restrict__ dest,
                                                     float* __restrict__ out) {
  int idx = blockIdx.x * 256 + threadIdx.x;  // NB*SEQ*96
  int row = idx / 96, c = idx % 96;
  size_t base_i = (size_t)row * DIM;
  float4 v = ((const float4*)(x + base_i))[c];
  float4 a = ((const float4*)(p0 + base_i))[c];
  float4 bb = ((const float4*)(p1 + base_i))[c];
  v.x += a.x + bb.x; v.y += a.y + bb.y; v.z += a.z + bb.z; v.w += a.w + bb.w;
  ((float4*)(out + base_i))[c] = v;
  int b = row >> 11;
  int d = dest[row];
  size_t base = (size_t)NB * SEQ * DIM;
  size_t o;
  if (d < 512) o = base + ((size_t)b * 512 + d) * DIM;
  else o = base + (size_t)NB * 512 * DIM + ((size_t)b * 1536 + (d - 512)) * DIM;
  ((float4*)(out + o))[c] = v;
}

extern "C" void kernel_launch(void* const* d_in, const int* in_sizes, int n_in,
                              void* d_out, int out_size, void* d_ws, size_t ws_size,
                              hipStream_t stream) {
  const float* vis = (const float*)d_in[0];
  const int* ids = (const int*)d_in[1];
  const int* mask = (const int*)d_in[2];
  const float* mask_token = (const float*)d_in[6];
  const float* ln_in_w = (const float*)d_in[7];
  const float* ln1_w = (const float*)d_in[8];
  const float* ln2_w = (const float*)d_in[9];
  const float* Wq = (const float*)d_in[10];
  const float* bq = (const float*)d_in[11];
  const float* Wk = (const float*)d_in[12];
  const float* bk = (const float*)d_in[13];
  const float* Wv = (const float*)d_in[14];
  const float* bv = (const float*)d_in[15];
  const float* Wo = (const float*)d_in[16];
  const float* bo = (const float*)d_in[17];
  const float* W1 = (const float*)d_in[18];
  const float* b1 = (const float*)d_in[19];
  const float* W2 = (const float*)d_in[20];
  const float* b2 = (const float*)d_in[21];

  char* p = (char*)d_ws;
  size_t off = 0;
  auto alloc = [&](size_t n) -> void* {
    off = (off + 255) & ~(size_t)255;
    void* r = p + off;
    off += n;
    return r;
  };
  unsigned short* wqkvT = (unsigned short*)alloc((size_t)NLAYER * 1152 * DIM * 2);
  unsigned short* woT = (unsigned short*)alloc((size_t)NLAYER * DIM * DIM * 2);
  unsigned short* w1T = (unsigned short*)alloc((size_t)NLAYER * DIM * FF * 2);
  unsigned short* w2T = (unsigned short*)alloc((size_t)NLAYER * DIM * FF * 2);
  float* bqkv = (float*)alloc((size_t)NLAYER * 1152 * 4);
  float* cosT = (float*)alloc((size_t)SEQ * HD * 4);
  float* sinT = (float*)alloc((size_t)SEQ * HD * 4);
  float* x = (float*)alloc((size_t)NB * SEQ * DIM * 4);
  unsigned short* hdn = (unsigned short*)alloc((size_t)NB * SEQ * DIM * 2);
  unsigned short* qpre = (unsigned short*)alloc((size_t)NB * SEQ * DIM * 2);
  unsigned short* kpre = (unsigned short*)alloc((size_t)NB * SEQ * DIM * 2);
  unsigned short* qb = (unsigned short*)alloc((size_t)NB * NH * SEQ * HDP * 2);
  unsigned short* kb = (unsigned short*)alloc((size_t)NB * NH * SEQ * HDP * 2);
  unsigned short* vtb = (unsigned short*)alloc((size_t)NB * NH * SEQ * HDP * 2);
  unsigned short* obuf = (unsigned short*)alloc((size_t)NB * SEQ * DIM * 2);
  unsigned short* a1 = (unsigned short*)alloc((size_t)NB * SEQ * FF * 2);
  float* pA0 = (float*)alloc((size_t)NB * SEQ * DIM * 4);
  float* pA1 = (float*)alloc((size_t)NB * SEQ * DIM * 4);
  float* pB0 = (float*)alloc((size_t)NB * SEQ * DIM * 4);
  float* pB1 = (float*)alloc((size_t)NB * SEQ * DIM * 4);
  int* dest = (int*)alloc((size_t)NB * SEQ * 4);

  // zero head-dim pad [48,64): q/k pads are contracted over by score MFMAs.
  hipMemsetAsync(qb, 0, (size_t)NB * NH * SEQ * HDP * 2, stream);
  hipMemsetAsync(kb, 0, (size_t)NB * NH * SEQ * HDP * 2, stream);

  dim3 tb(32, 8);
  wtrans_kernel<<<dim3(12, 12, 8), tb, 0, stream>>>(Wq, wqkvT, 384, 384, 147456, 442368);
  wtrans_kernel<<<dim3(12, 12, 8), tb, 0, stream>>>(Wk, wqkvT + 147456, 384, 384, 147456, 442368);
  wtrans_kernel<<<dim3(12, 12, 8), tb, 0, stream>>>(Wv, wqkvT + 294912, 384, 384, 147456, 442368);
  wtrans_kernel<<<dim3(12, 12, 8), tb, 0, stream>>>(Wo, woT, 384, 384, 147456, 147456);
  wtrans_kernel<<<dim3(48, 12, 8), tb, 0, stream>>>(W1, w1T, 384, 1536, 589824, 589824);
  wtrans_kernel<<<dim3(12, 48, 8), tb, 0, stream>>>(W2, w2T, 1536, 384, 589824, 589824);
  biascat_kernel<<<(NLAYER * 1152 + 255) / 256, 256, 0, stream>>>(bq, bk, bv, bqkv);
  ropetab_kernel<<<(SEQ * HD + 255) / 256, 256, 0, stream>>>(cosT, sinT);
  gatherrms_kernel<<<NB * SEQ / 4, 256, 0, stream>>>(vis, ids, mask_token, ln_in_w, x);

  for (int i = 0; i < NLAYER; i++) {
    size_t wo = (size_t)i * DIM * DIM;
    size_t wf = (size_t)i * DIM * FF;
    rmsadd_kernel<<<NB * SEQ / 4, 256, 0, stream>>>(x, pB0, pB1, ln1_w + i * DIM, hdn, i > 0);
    gemm64_kernel<<<dim3(64, 18, 1), 256, 0, stream>>>(hdn, wqkvT + (size_t)i * 442368,
                                                       bqkv + i * 1152, NB * SEQ, 1152, DIM, 4,
                                                       qpre, kpre, vtb, nullptr, nullptr);
    rope_kernel<<<NB * SEQ, 384, 0, stream>>>(qpre, kpre, cosT, sinT, qb, kb);
    fattn_kernel<<<512, 256, 0, stream>>>(qb, kb, vtb, obuf);
    gemm64_kernel<<<dim3(64, 6, 2), 256, 0, stream>>>(obuf, woT + wo, bo + i * DIM, NB * SEQ, DIM,
                                                      DIM, 5, nullptr, nullptr, nullptr, pA0, pA1);
    rmsadd_kernel<<<NB * SEQ / 4, 256, 0, stream>>>(x, pA0, pA1, ln2_w + i * DIM, hdn, 1);
    gemm64_kernel<<<dim3(64, 24, 1), 256, 0, stream>>>(hdn, w1T + wf, b1 + i * FF, NB * SEQ, FF,
                                                       DIM, 3, a1, nullptr, nullptr, nullptr,
                                                       nullptr);
    gemm64_kernel<<<dim3(64, 6, 2), 256, 0, stream>>>(a1, w2T + wf, b2 + i * DIM, NB * SEQ, DIM,
                                                      FF, 5, nullptr, nullptr, nullptr, pB0, pB1);
  }
  rank_kernel<<<NB, 256, 0, stream>>>(mask, dest);
  output_kernel<<<NB * SEQ * 96 / 256, 256, 0, stream>>>(x, pB0, pB1, dest, (float*)d_out);
}

// Round 7
// 1053.156 us; speedup vs baseline: 1.4879x; 1.0908x over previous
//
#include <hip/hip_runtime.h>

typedef __attribute__((ext_vector_type(8))) __bf16 bf16x8;
typedef __attribute__((ext_vector_type(8))) unsigned short ushort8;
typedef __attribute__((ext_vector_type(4))) float floatx4;

#define NB 2
#define SEQ 2048
#define DIM 384
#define NH 8
#define HD 48
#define HDP 64
#define FF 1536
#define NLAYER 8
#define ATT_SCALE 0.14433756729740643f  // 1/sqrt(48)

__device__ __forceinline__ unsigned short f2bf(float f) {
  unsigned u = __builtin_bit_cast(unsigned, f);
  u += 0x7fffu + ((u >> 16) & 1u);
  return (unsigned short)(u >> 16);
}
__device__ __forceinline__ float bf2f(unsigned short h) {
  unsigned u = ((unsigned)h) << 16;
  return __builtin_bit_cast(float, u);
}
__device__ __forceinline__ bf16x8 ldb8(const unsigned short* p) {
  return __builtin_bit_cast(bf16x8, *(const ushort8*)p);
}
__device__ __forceinline__ void gl2lds16(const unsigned short* g, unsigned short* l) {
  __builtin_amdgcn_global_load_lds((const __attribute__((address_space(1))) unsigned int*)g,
                                   (__attribute__((address_space(3))) unsigned int*)l, 16, 0, 0);
}
#define MFMA(a, b, c) __builtin_amdgcn_mfma_f32_16x16x32_bf16(a, b, c, 0, 0, 0)

// ---------------- weight transpose+convert: W (K x N) fp32 -> Wt (N x K) bf16 ----
__global__ __launch_bounds__(256) void wtrans_kernel(const float* __restrict__ W,
                                                     unsigned short* __restrict__ Wt,
                                                     int K, int N,
                                                     size_t sstride, size_t dstride) {
  __shared__ unsigned short tile[32][33];
  const float* Wl = W + (size_t)blockIdx.z * sstride;
  unsigned short* Wtl = Wt + (size_t)blockIdx.z * dstride;
  int n0 = blockIdx.x * 32, k0 = blockIdx.y * 32;
  int tx = threadIdx.x, ty = threadIdx.y;  // block (32,8)
  for (int i = ty; i < 32; i += 8)
    tile[i][tx] = f2bf(Wl[(size_t)(k0 + i) * N + n0 + tx]);
  __syncthreads();
  for (int i = ty; i < 32; i += 8)
    Wtl[(size_t)(n0 + i) * K + k0 + tx] = tile[tx][i];
}

// ---------------- qkv bias concat [8][1152] ----------------
__global__ void biascat_kernel(const float* __restrict__ bq, const float* __restrict__ bk,
                               const float* __restrict__ bv, float* __restrict__ out) {
  int idx = blockIdx.x * 256 + threadIdx.x;
  if (idx >= NLAYER * 1152) return;
  int z = idx / 1152, j = idx % 1152;
  float v = (j < 384) ? bq[z * 384 + j] : (j < 768) ? bk[z * 384 + j - 384] : bv[z * 384 + j - 768];
  out[idx] = v;
}

// ---------------- rope tables ----------------
__global__ void ropetab_kernel(float* __restrict__ cosT, float* __restrict__ sinT) {
  int idx = blockIdx.x * 256 + threadIdx.x;
  if (idx >= SEQ * HD) return;
  int l = idx / HD, d = idx % HD;
  int j = d % 24;
  float inv = powf(10000.0f, -(float)j / 24.0f);
  float pos;
  if (j < 6) pos = (float)(l >> 8);
  else if (j < 15) pos = (float)((l >> 4) & 15);
  else pos = (float)(l & 15);
  float f = pos * inv;
  cosT[idx] = cosf(f);
  sinT[idx] = sinf(f);
}

// ---------------- gather (ids_restore) + input RMS -> fp32 stream x ----------------
__global__ __launch_bounds__(256) void gatherrms_kernel(const float* __restrict__ vis,
                                                        const int* __restrict__ ids,
                                                        const float* __restrict__ mask_token,
                                                        const float* __restrict__ w,
                                                        float* __restrict__ x) {
  int wv = threadIdx.x >> 6, lane = threadIdx.x & 63;
  int row = blockIdx.x * 4 + wv;  // b*2048 + l
  int b = row >> 11;
  int src = ids[row];
  const float* p = (src < 512) ? (vis + ((size_t)b * 512 + src) * DIM) : mask_token;
  float v[6];
  float ss = 0.f;
#pragma unroll
  for (int j = 0; j < 6; j++) { v[j] = p[lane + 64 * j]; ss += v[j] * v[j]; }
#pragma unroll
  for (int m = 32; m; m >>= 1) ss += __shfl_xor(ss, m);
  float s = rsqrtf(ss * (1.0f / DIM) + 1e-6f);
#pragma unroll
  for (int j = 0; j < 6; j++)
    x[(size_t)row * DIM + lane + 64 * j] = v[j] * s * w[lane + 64 * j];
}

// ---------------- fused: x += p0+p1 (optional), then RMS -> bf16 out ----------------
__global__ __launch_bounds__(256) void rmsadd_kernel(float* __restrict__ x,
                                                     const float* __restrict__ p0,
                                                     const float* __restrict__ p1,
                                                     const float* __restrict__ w,
                                                     unsigned short* __restrict__ out,
                                                     int doadd) {
  int wv = threadIdx.x >> 6, lane = threadIdx.x & 63;
  int row = blockIdx.x * 4 + wv;
  size_t base = (size_t)row * DIM;
  float v[6];
  float ss = 0.f;
  if (doadd) {
#pragma unroll
    for (int j = 0; j < 6; j++) {
      int o = lane + 64 * j;
      v[j] = x[base + o] + p0[base + o] + p1[base + o];
      x[base + o] = v[j];
      ss += v[j] * v[j];
    }
  } else {
#pragma unroll
    for (int j = 0; j < 6; j++) { v[j] = x[base + lane + 64 * j]; ss += v[j] * v[j]; }
  }
#pragma unroll
  for (int m = 32; m; m >>= 1) ss += __shfl_xor(ss, m);
  float s = rsqrtf(ss * (1.0f / DIM) + 1e-6f);
#pragma unroll
  for (int j = 0; j < 6; j++)
    out[base + lane + 64 * j] = f2bf(v[j] * s * w[lane + 64 * j]);
}

// ---------------- unified 64x64-tile GEMM, global_load_lds staging, optional split-K ------
// mode 3: gelu -> outb bf16
// mode 4: qkv split: n<384 -> outb (q), <768 -> outb2 (k), else v -> outv[b][h][hd][l]
// mode 5: fp32 partial to (z==0 ? outf0 : outf1); bias added by z==0 only
__global__ __launch_bounds__(256) void gemm64_kernel(const unsigned short* __restrict__ A,
                                                     const unsigned short* __restrict__ Wt,
                                                     const float* __restrict__ bias,
                                                     int M, int N, int K, int mode,
                                                     unsigned short* __restrict__ outb,
                                                     unsigned short* __restrict__ outb2,
                                                     unsigned short* __restrict__ outv,
                                                     float* __restrict__ outf0,
                                                     float* __restrict__ outf1) {
  __shared__ __align__(16) unsigned short As[64 * 32];
  __shared__ __align__(16) unsigned short Bs[64 * 32];
  int tid = threadIdx.x;
  int wv = tid >> 6, lane = tid & 63;
  int wm = wv >> 1, wn = wv & 1;
  int row0 = blockIdx.x * 64, col0 = blockIdx.y * 64;
  int q = lane >> 4, c = lane & 15;
  int kchunk = K / gridDim.z;
  int kb0 = blockIdx.z * kchunk;
  floatx4 acc[2][2] = {};
  int sr = tid >> 2, sk = (tid & 3) * 8;
  const unsigned short* Ag = A + (size_t)(row0 + sr) * K + kb0 + sk;
  const unsigned short* Bg = Wt + (size_t)(col0 + sr) * K + kb0 + sk;
  unsigned short* Asl = As + tid * 8;
  unsigned short* Bsl = Bs + tid * 8;
  for (int k0 = 0; k0 < kchunk; k0 += 32) {
    gl2lds16(Ag + k0, Asl);
    gl2lds16(Bg + k0, Bsl);
    __syncthreads();
    bf16x8 a0 = ldb8(&As[(wm * 32 + c) * 32 + q * 8]);
    bf16x8 a1 = ldb8(&As[(wm * 32 + 16 + c) * 32 + q * 8]);
    bf16x8 b0 = ldb8(&Bs[(wn * 32 + c) * 32 + q * 8]);
    bf16x8 b1 = ldb8(&Bs[(wn * 32 + 16 + c) * 32 + q * 8]);
    acc[0][0] = MFMA(a0, b0, acc[0][0]);
    acc[0][1] = MFMA(a0, b1, acc[0][1]);
    acc[1][0] = MFMA(a1, b0, acc[1][0]);
    acc[1][1] = MFMA(a1, b1, acc[1][1]);
    __syncthreads();
  }
  float* outf = blockIdx.z ? outf1 : outf0;
  int addb = (blockIdx.z == 0);
#pragma unroll
  for (int tm = 0; tm < 2; tm++)
#pragma unroll
    for (int tn = 0; tn < 2; tn++)
#pragma unroll
      for (int r = 0; r < 4; r++) {
        int rg = row0 + wm * 32 + tm * 16 + q * 4 + r;
        int cg = col0 + wn * 32 + tn * 16 + c;
        float v = acc[tm][tn][r] + (addb ? bias[cg] : 0.f);
        if (mode == 3) {
          float g = v * 0.5f * (1.0f + erff(v * 0.70710678f));
          outb[(size_t)rg * N + cg] = f2bf(g);
        } else if (mode == 4) {
          if (cg < 384) {
            outb[(size_t)rg * 384 + cg] = f2bf(v);
          } else if (cg < 768) {
            outb2[(size_t)rg * 384 + cg - 384] = f2bf(v);
          } else {
            int j = cg - 768;
            int h = j / HD, hd = j % HD;
            int b = rg >> 11, l = rg & 2047;
            outv[(((size_t)b * NH + h) * HDP + hd) * SEQ + l] = f2bf(v);
          }
        } else {  // mode 5
          outf[(size_t)rg * N + cg] = v;
        }
      }
}

// ---------------- rope: qpre/kpre (bf16 row-major) -> q/k [b][h][l][64]; q scaled ----------
__global__ __launch_bounds__(384) void rope_kernel(const unsigned short* __restrict__ qpre,
                                                   const unsigned short* __restrict__ kpre,
                                                   const float* __restrict__ cosT,
                                                   const float* __restrict__ sinT,
                                                   unsigned short* __restrict__ qdst,
                                                   unsigned short* __restrict__ kdst) {
  int row = blockIdx.x;  // b*2048 + l
  int b = row >> 11, l = row & 2047;
  int t = threadIdx.x;
  const unsigned short* src = (t >= 192) ? kpre : qpre;
  unsigned short* dst = (t >= 192) ? kdst : qdst;
  float sc = (t >= 192) ? 1.0f : ATT_SCALE;  // fold 1/sqrt(hd) into q
  int pp = t % 192;
  int h = pp / 24, d = pp % 24;
  float x1 = bf2f(src[(size_t)row * DIM + h * HD + d]);
  float x2 = bf2f(src[(size_t)row * DIM + h * HD + d + 24]);
  float cs = cosT[l * HD + d], sn = sinT[l * HD + d];
  size_t base = (((size_t)b * NH + h) * SEQ + l) * HDP;
  dst[base + d] = f2bf((x1 * cs - x2 * sn) * sc);
  dst[base + d + 24] = f2bf((x2 * cs + x1 * sn) * sc);
}

// ---------------- flash attention v7: dbuf K/V staging + 2-way K-split + partials ---------
// block i: bh = 2*(i&7)+((i>>3)&1) (XCD swizzle), rest=i>>4: z=rest&1, q0=(rest>>1)*64.
// wave wv owns q-rows q0+wv*16.. ; handles iters [z*n2, min(n, z*n2+n2)) of 64 keys.
// Double-buffered LDS K/V: one barrier per iter; global loads for it+1 in flight
// during compute of it. Partial (unnormalized O, m, l) -> fp32 ws, merged by amerge.
__global__ __launch_bounds__(256) void fattn_kernel(const unsigned short* __restrict__ qb,
                                                    const unsigned short* __restrict__ kb,
                                                    const unsigned short* __restrict__ vt,
                                                    float* __restrict__ pO,
                                                    float* __restrict__ pM,
                                                    float* __restrict__ pL) {
  __shared__ __align__(16) unsigned short Ks[2][64][72];
  __shared__ __align__(16) unsigned short Vs[2][48][72];
  __shared__ __align__(16) unsigned short Pt[4][16][64];
  int tid = threadIdx.x;
  int wv = tid >> 6, lane = tid & 63;
  int q = lane >> 4, c = lane & 15;
  int i = blockIdx.x;
  int bh = 2 * (i & 7) + ((i >> 3) & 1);
  int rest = i >> 4;
  int z = rest & 1;
  int q0 = (rest >> 1) * 64;
  int kstart = q0 & ~255;  // frame-aligned reverse-causal mask
  int n = (SEQ - kstart) >> 6;
  int n2 = (n + 1) >> 1;
  int it0 = z * n2;
  int it1 = z ? n : n2;
  const unsigned short* qbase = qb + (size_t)bh * SEQ * HDP;
  const unsigned short* kbase = kb + (size_t)bh * SEQ * HDP;
  const unsigned short* vbase = vt + (size_t)bh * HDP * SEQ;
  int myrow = q0 + wv * 16;
  bf16x8 a0 = ldb8(qbase + (size_t)(myrow + c) * HDP + q * 8);
  bf16x8 a1 = ldb8(qbase + (size_t)(myrow + c) * HDP + 32 + q * 8);
  floatx4 O[3] = {};
  float mr[4] = {-3e38f, -3e38f, -3e38f, -3e38f};
  float lr[4] = {0.f, 0.f, 0.f, 0.f};
  int srow = tid >> 2, sch = (tid & 3) * 16;
  ushort8 kA, kB, vA, vB;
  const unsigned short* kg0 = kbase + (size_t)srow * HDP + sch;
  const unsigned short* vg0 = vbase + (size_t)srow * SEQ + sch;
  // prologue loads
  {
    int k0 = kstart + it0 * 64;
    kA = *(const ushort8*)(kg0 + (size_t)k0 * HDP);
    kB = *(const ushort8*)(kg0 + (size_t)k0 * HDP + 8);
    if (srow < 48) {
      vA = *(const ushort8*)(vg0 + k0);
      vB = *(const ushort8*)(vg0 + k0 + 8);
    }
  }
  for (int it = it0; it < it1; ++it) {
    int buf = it & 1;
    *(ushort8*)(&Ks[buf][srow][sch]) = kA;
    *(ushort8*)(&Ks[buf][srow][sch + 8]) = kB;
    if (srow < 48) {
      *(ushort8*)(&Vs[buf][srow][sch]) = vA;
      *(ushort8*)(&Vs[buf][srow][sch + 8]) = vB;
    }
    if (it + 1 < it1) {  // issue next tile's loads; in flight during compute
      int k0 = kstart + (it + 1) * 64;
      kA = *(const ushort8*)(kg0 + (size_t)k0 * HDP);
      kB = *(const ushort8*)(kg0 + (size_t)k0 * HDP + 8);
      if (srow < 48) {
        vA = *(const ushort8*)(vg0 + k0);
        vB = *(const ushort8*)(vg0 + k0 + 8);
      }
    }
    __syncthreads();
    floatx4 S[4];
#pragma unroll
    for (int t = 0; t < 4; t++) {
      bf16x8 b0 = ldb8(&Ks[buf][t * 16 + c][q * 8]);
      bf16x8 b1 = ldb8(&Ks[buf][t * 16 + c][32 + q * 8]);
      floatx4 zz = {};
      zz = MFMA(a0, b0, zz);
      S[t] = MFMA(a1, b1, zz);
    }
    float alpha[4];
#pragma unroll
    for (int r = 0; r < 4; r++) {
      float m0 = fmaxf(fmaxf(S[0][r], S[1][r]), fmaxf(S[2][r], S[3][r]));
#pragma unroll
      for (int msk = 1; msk < 16; msk <<= 1) m0 = fmaxf(m0, __shfl_xor(m0, msk, 16));
      float nm = fmaxf(mr[r], m0);
      alpha[r] = __expf(mr[r] - nm);
      mr[r] = nm;
      lr[r] *= alpha[r];
    }
#pragma unroll
    for (int t = 0; t < 4; t++)
#pragma unroll
      for (int r = 0; r < 4; r++) {
        float pv = __expf(S[t][r] - mr[r]);
        lr[r] += pv;
        Pt[wv][q * 4 + r][t * 16 + c] = f2bf(pv);
      }
#pragma unroll
    for (int f = 0; f < 3; f++)
#pragma unroll
      for (int r = 0; r < 4; r++) O[f][r] *= alpha[r];
    bf16x8 pa0 = ldb8(&Pt[wv][c][q * 8]);
    bf16x8 pa1 = ldb8(&Pt[wv][c][32 + q * 8]);
#pragma unroll
    for (int f = 0; f < 3; f++) {
      bf16x8 v0 = ldb8(&Vs[buf][f * 16 + c][q * 8]);
      bf16x8 v1 = ldb8(&Vs[buf][f * 16 + c][32 + q * 8]);
      O[f] = MFMA(pa0, v0, O[f]);
      O[f] = MFMA(pa1, v1, O[f]);
    }
    // no trailing barrier: next iter writes the other buffer; re-write of this
    // buffer happens after the NEXT barrier, by which time all waves are past
    // their reads of it (one barrier per iteration is sufficient with 2 bufs).
  }
#pragma unroll
  for (int r = 0; r < 4; r++)
#pragma unroll
    for (int msk = 1; msk < 16; msk <<= 1) lr[r] += __shfl_xor(lr[r], msk, 16);
  size_t pbase = (size_t)z * (NB * NH * SEQ) + (size_t)bh * SEQ + myrow;
#pragma unroll
  for (int r = 0; r < 4; r++) {
    int row = q * 4 + r;
    if (c == 0) {
      pM[pbase + row] = mr[r];
      pL[pbase + row] = lr[r];
    }
#pragma unroll
    for (int f = 0; f < 3; f++) pO[(pbase + row) * 48 + f * 16 + c] = O[f][r];
  }
}

// ---------------- merge the two K-split partials -> obuf bf16 row-major -------------------
__global__ __launch_bounds__(256) void amerge_kernel(const float* __restrict__ pO,
                                                     const float* __restrict__ pM,
                                                     const float* __restrict__ pL,
                                                     unsigned short* __restrict__ obuf) {
  int idx = blockIdx.x * 256 + threadIdx.x;  // 16*2048*48
  int rowg = idx / 48, d = idx - rowg * 48;
  const int NR = NB * NH * SEQ;
  float m0 = pM[rowg], m1 = pM[NR + rowg];
  float l0 = pL[rowg], l1 = pL[NR + rowg];
  float M = fmaxf(m0, m1);
  float e0 = __expf(m0 - M), e1 = __expf(m1 - M);
  float inv = 1.0f / (l0 * e0 + l1 * e1);
  float v = (pO[(size_t)rowg * 48 + d] * e0 + pO[(size_t)(NR + rowg) * 48 + d] * e1) * inv;
  int bh = rowg >> 11, l = rowg & 2047;
  obuf[(((size_t)(bh >> 3)) * SEQ + l) * DIM + (bh & 7) * HD + d] = f2bf(v);
}

// ---------------- stable argsort(-mask) ranks via block scan ----------------
__global__ __launch_bounds__(256) void rank_kernel(const int* __restrict__ mask,
                                                   int* __restrict__ dest) {
  __shared__ int wsum[4];
  int b = blockIdx.x, t = threadIdx.x;
  int lane = t & 63, wv = t >> 6;
  const int* mb = mask + b * SEQ;
  int base = t * 8;
  int v[8];
  int s = 0;
#pragma unroll
  for (int j = 0; j < 8; j++) { v[j] = mb[base + j]; s += v[j]; }
  int incl = s;
  for (int off = 1; off < 64; off <<= 1) {
    int n = __shfl_up(incl, off);
    if (lane >= off) incl += n;
  }
  if (lane == 63) wsum[wv] = incl;
  __syncthreads();
  int P = incl - s;
  for (int w = 0; w < wv; w++) P += wsum[w];
  int run = 0;
#pragma unroll
  for (int j = 0; j < 8; j++) {
    int ones = P + run;
    int l = base + j;
    dest[b * SEQ + l] = v[j] ? ones : 512 + (l - ones);
    run += v[j];
  }
}

// ---------------- final: x+p0+p1 -> decoded_full + scattered visible/masked ----------------
__global__ __launch_bounds__(256) void output_kernel(const float* __restrict__ x,
                                                     const float* __restrict__ p0,
                                                     const float* __restrict__ p1,
                                                     const int* __restrict__ dest,
                                                     float* __restrict__ out) {
  int idx = blockIdx.x * 256 + threadIdx.x;  // NB*SEQ*96
  int row = idx / 96, c = idx % 96;
  size_t base_i = (size_t)row * DIM;
  float4 v = ((const float4*)(x + base_i))[c];
  float4 a = ((const float4*)(p0 + base_i))[c];
  float4 bb = ((const float4*)(p1 + base_i))[c];
  v.x += a.x + bb.x; v.y += a.y + bb.y; v.z += a.z + bb.z; v.w += a.w + bb.w;
  ((float4*)(out + base_i))[c] = v;
  int b = row >> 11;
  int d = dest[row];
  size_t base = (size_t)NB * SEQ * DIM;
  size_t o;
  if (d < 512) o = base + ((size_t)b * 512 + d) * DIM;
  else o = base + (size_t)NB * 512 * DIM + ((size_t)b * 1536 + (d - 512)) * DIM;
  ((float4*)(out + o))[c] = v;
}

extern "C" void kernel_launch(void* const* d_in, const int* in_sizes, int n_in,
                              void* d_out, int out_size, void* d_ws, size_t ws_size,
                              hipStream_t stream) {
  const float* vis = (const float*)d_in[0];
  const int* ids = (const int*)d_in[1];
  const int* mask = (const int*)d_in[2];
  const float* mask_token = (const float*)d_in[6];
  const float* ln_in_w = (const float*)d_in[7];
  const float* ln1_w = (const float*)d_in[8];
  const float* ln2_w = (const float*)d_in[9];
  const float* Wq = (const float*)d_in[10];
  const float* bq = (const float*)d_in[11];
  const float* Wk = (const float*)d_in[12];
  const float* bk = (const float*)d_in[13];
  const float* Wv = (const float*)d_in[14];
  const float* bv = (const float*)d_in[15];
  const float* Wo = (const float*)d_in[16];
  const float* bo = (const float*)d_in[17];
  const float* W1 = (const float*)d_in[18];
  const float* b1 = (const float*)d_in[19];
  const float* W2 = (const float*)d_in[20];
  const float* b2 = (const float*)d_in[21];

  char* p = (char*)d_ws;
  size_t off = 0;
  auto alloc = [&](size_t n) -> void* {
    off = (off + 255) & ~(size_t)255;
    void* r = p + off;
    off += n;
    return r;
  };
  unsigned short* wqkvT = (unsigned short*)alloc((size_t)NLAYER * 1152 * DIM * 2);
  unsigned short* woT = (unsigned short*)alloc((size_t)NLAYER * DIM * DIM * 2);
  unsigned short* w1T = (unsigned short*)alloc((size_t)NLAYER * DIM * FF * 2);
  unsigned short* w2T = (unsigned short*)alloc((size_t)NLAYER * DIM * FF * 2);
  float* bqkv = (float*)alloc((size_t)NLAYER * 1152 * 4);
  float* cosT = (float*)alloc((size_t)SEQ * HD * 4);
  float* sinT = (float*)alloc((size_t)SEQ * HD * 4);
  float* x = (float*)alloc((size_t)NB * SEQ * DIM * 4);
  unsigned short* hdn = (unsigned short*)alloc((size_t)NB * SEQ * DIM * 2);
  unsigned short* qpre = (unsigned short*)alloc((size_t)NB * SEQ * DIM * 2);
  unsigned short* kpre = (unsigned short*)alloc((size_t)NB * SEQ * DIM * 2);
  unsigned short* qb = (unsigned short*)alloc((size_t)NB * NH * SEQ * HDP * 2);
  unsigned short* kb = (unsigned short*)alloc((size_t)NB * NH * SEQ * HDP * 2);
  unsigned short* vtb = (unsigned short*)alloc((size_t)NB * NH * SEQ * HDP * 2);
  unsigned short* obuf = (unsigned short*)alloc((size_t)NB * SEQ * DIM * 2);
  unsigned short* a1 = (unsigned short*)alloc((size_t)NB * SEQ * FF * 2);
  float* pA0 = (float*)alloc((size_t)NB * SEQ * DIM * 4);
  float* pA1 = (float*)alloc((size_t)NB * SEQ * DIM * 4);
  float* pB0 = (float*)alloc((size_t)NB * SEQ * DIM * 4);
  float* pB1 = (float*)alloc((size_t)NB * SEQ * DIM * 4);
  float* pO = (float*)alloc((size_t)2 * NB * NH * SEQ * 48 * 4);
  float* pM = (float*)alloc((size_t)2 * NB * NH * SEQ * 4);
  float* pL = (float*)alloc((size_t)2 * NB * NH * SEQ * 4);
  int* dest = (int*)alloc((size_t)NB * SEQ * 4);

  // zero head-dim pad [48,64): q/k pads are contracted over by score MFMAs.
  hipMemsetAsync(qb, 0, (size_t)NB * NH * SEQ * HDP * 2, stream);
  hipMemsetAsync(kb, 0, (size_t)NB * NH * SEQ * HDP * 2, stream);

  dim3 tb(32, 8);
  wtrans_kernel<<<dim3(12, 12, 8), tb, 0, stream>>>(Wq, wqkvT, 384, 384, 147456, 442368);
  wtrans_kernel<<<dim3(12, 12, 8), tb, 0, stream>>>(Wk, wqkvT + 147456, 384, 384, 147456, 442368);
  wtrans_kernel<<<dim3(12, 12, 8), tb, 0, stream>>>(Wv, wqkvT + 294912, 384, 384, 147456, 442368);
  wtrans_kernel<<<dim3(12, 12, 8), tb, 0, stream>>>(Wo, woT, 384, 384, 147456, 147456);
  wtrans_kernel<<<dim3(48, 12, 8), tb, 0, stream>>>(W1, w1T, 384, 1536, 589824, 589824);
  wtrans_kernel<<<dim3(12, 48, 8), tb, 0, stream>>>(W2, w2T, 1536, 384, 589824, 589824);
  biascat_kernel<<<(NLAYER * 1152 + 255) / 256, 256, 0, stream>>>(bq, bk, bv, bqkv);
  ropetab_kernel<<<(SEQ * HD + 255) / 256, 256, 0, stream>>>(cosT, sinT);
  gatherrms_kernel<<<NB * SEQ / 4, 256, 0, stream>>>(vis, ids, mask_token, ln_in_w, x);

  for (int i = 0; i < NLAYER; i++) {
    size_t wo = (size_t)i * DIM * DIM;
    size_t wf = (size_t)i * DIM * FF;
    rmsadd_kernel<<<NB * SEQ / 4, 256, 0, stream>>>(x, pB0, pB1, ln1_w + i * DIM, hdn, i > 0);
    gemm64_kernel<<<dim3(64, 18, 1), 256, 0, stream>>>(hdn, wqkvT + (size_t)i * 442368,
                                                       bqkv + i * 1152, NB * SEQ, 1152, DIM, 4,
                                                       qpre, kpre, vtb, nullptr, nullptr);
    rope_kernel<<<NB * SEQ, 384, 0, stream>>>(qpre, kpre, cosT, sinT, qb, kb);
    fattn_kernel<<<1024, 256, 0, stream>>>(qb, kb, vtb, pO, pM, pL);
    amerge_kernel<<<NB * NH * SEQ * 48 / 256, 256, 0, stream>>>(pO, pM, pL, obuf);
    gemm64_kernel<<<dim3(64, 6, 2), 256, 0, stream>>>(obuf, woT + wo, bo + i * DIM, NB * SEQ, DIM,
                                                      DIM, 5, nullptr, nullptr, nullptr, pA0, pA1);
    rmsadd_kernel<<<NB * SEQ / 4, 256, 0, stream>>>(x, pA0, pA1, ln2_w + i * DIM, hdn, 1);
    gemm64_kernel<<<dim3(64, 24, 1), 256, 0, stream>>>(hdn, w1T + wf, b1 + i * FF, NB * SEQ, FF,
                                                       DIM, 3, a1, nullptr, nullptr, nullptr,
                                                       nullptr);
    gemm64_kernel<<<dim3(64, 6, 2), 256, 0, stream>>>(a1, w2T + wf, b2 + i * DIM, NB * SEQ, DIM,
                                                      FF, 5, nullptr, nullptr, nullptr, pB0, pB1);
  }
  rank_kernel<<<NB, 256, 0, stream>>>(mask, dest);
  output_kernel<<<NB * SEQ * 96 / 256, 256, 0, stream>>>(x, pB0, pB1, dest, (float*)d_out);
}

// Round 8
// 935.732 us; speedup vs baseline: 1.6746x; 1.1255x over previous
//
#include <hip/hip_runtime.h>

typedef __attribute__((ext_vector_type(8))) __bf16 bf16x8;
typedef __attribute__((ext_vector_type(8))) unsigned short ushort8;
typedef __attribute__((ext_vector_type(4))) float floatx4;

#define NB 2
#define SEQ 2048
#define DIM 384
#define NH 8
#define HD 48
#define HDP 64
#define FF 1536
#define NLAYER 8
#define NRG (NB * NH * SEQ)
#define ATT_SCALE 0.14433756729740643f  // 1/sqrt(48)

__device__ __forceinline__ unsigned short f2bf(float f) {
  unsigned u = __builtin_bit_cast(unsigned, f);
  u += 0x7fffu + ((u >> 16) & 1u);
  return (unsigned short)(u >> 16);
}
__device__ __forceinline__ float bf2f(unsigned short h) {
  unsigned u = ((unsigned)h) << 16;
  return __builtin_bit_cast(float, u);
}
__device__ __forceinline__ bf16x8 ldb8(const unsigned short* p) {
  return __builtin_bit_cast(bf16x8, *(const ushort8*)p);
}
__device__ __forceinline__ void gl2lds16(const unsigned short* g, unsigned short* l) {
  __builtin_amdgcn_global_load_lds((const __attribute__((address_space(1))) unsigned int*)g,
                                   (__attribute__((address_space(3))) unsigned int*)l, 16, 0, 0);
}
#define MFMA(a, b, c) __builtin_amdgcn_mfma_f32_16x16x32_bf16(a, b, c, 0, 0, 0)

// ---- weight transpose+convert: W (K x N) fp32 -> Wt (N x K) bf16; permqk interleaves
// rope pairs within each head: d<24 -> 2d, d>=24 -> 2(d-24)+1 (same perm for q,k => QK^T invariant)
__global__ __launch_bounds__(256) void wtrans_kernel(const float* __restrict__ W,
                                                     unsigned short* __restrict__ Wt,
                                                     int K, int N, size_t sstride, size_t dstride,
                                                     int permqk) {
  __shared__ unsigned short tile[32][33];
  const float* Wl = W + (size_t)blockIdx.z * sstride;
  unsigned short* Wtl = Wt + (size_t)blockIdx.z * dstride;
  int n0 = blockIdx.x * 32, k0 = blockIdx.y * 32;
  int tx = threadIdx.x, ty = threadIdx.y;  // block (32,8)
  for (int i = ty; i < 32; i += 8)
    tile[i][tx] = f2bf(Wl[(size_t)(k0 + i) * N + n0 + tx]);
  __syncthreads();
  for (int i = ty; i < 32; i += 8) {
    int n = n0 + i;
    if (permqk) {
      int h = n / 48, d = n % 48;
      n = h * 48 + (d < 24 ? 2 * d : 2 * (d - 24) + 1);
    }
    Wtl[(size_t)n * K + k0 + tx] = tile[tx][i];
  }
}

// ---- qkv bias concat [8][1152], q/k parts rope-permuted ----
__global__ void biascat_kernel(const float* __restrict__ bq, const float* __restrict__ bk,
                               const float* __restrict__ bv, float* __restrict__ out) {
  int idx = blockIdx.x * 256 + threadIdx.x;
  if (idx >= NLAYER * 1152) return;
  int z = idx / 1152, j = idx % 1152;
  int part = j / 384, jj = j % 384;
  float v = (part == 0) ? bq[z * 384 + jj] : (part == 1) ? bk[z * 384 + jj] : bv[z * 384 + jj];
  int dst = j;
  if (part < 2) {
    int h = jj / 48, d = jj % 48;
    dst = part * 384 + h * 48 + (d < 24 ? 2 * d : 2 * (d - 24) + 1);
  }
  out[z * 1152 + dst] = v;
}

// ---- packed rope table: cs2[l*24+f] = (cos, sin) ----
__global__ void ropetab_kernel(float2* __restrict__ cs2) {
  int idx = blockIdx.x * 256 + threadIdx.x;
  if (idx >= SEQ * 24) return;
  int l = idx / 24, f = idx % 24;
  float inv = powf(10000.0f, -(float)f / 24.0f);
  float pos;
  if (f < 6) pos = (float)(l >> 8);
  else if (f < 15) pos = (float)((l >> 4) & 15);
  else pos = (float)(l & 15);
  float ang = pos * inv;
  cs2[idx] = make_float2(cosf(ang), sinf(ang));
}

// ---- gather (ids_restore) + input RMS -> fp32 stream x ----
__global__ __launch_bounds__(256) void gatherrms_kernel(const float* __restrict__ vis,
                                                        const int* __restrict__ ids,
                                                        const float* __restrict__ mask_token,
                                                        const float* __restrict__ w,
                                                        float* __restrict__ x) {
  int wv = threadIdx.x >> 6, lane = threadIdx.x & 63;
  int row = blockIdx.x * 4 + wv;
  int b = row >> 11;
  int src = ids[row];
  const float* p = (src < 512) ? (vis + ((size_t)b * 512 + src) * DIM) : mask_token;
  float v[6];
  float ss = 0.f;
#pragma unroll
  for (int j = 0; j < 6; j++) { v[j] = p[lane + 64 * j]; ss += v[j] * v[j]; }
#pragma unroll
  for (int m = 32; m; m >>= 1) ss += __shfl_xor(ss, m);
  float s = rsqrtf(ss * (1.0f / DIM) + 1e-6f);
#pragma unroll
  for (int j = 0; j < 6; j++)
    x[(size_t)row * DIM + lane + 64 * j] = v[j] * s * w[lane + 64 * j];
}

// ---- fused: x += p0+p1 (optional), then RMS -> bf16 out ----
__global__ __launch_bounds__(256) void rmsadd_kernel(float* __restrict__ x,
                                                     const float* __restrict__ p0,
                                                     const float* __restrict__ p1,
                                                     const float* __restrict__ w,
                                                     unsigned short* __restrict__ out,
                                                     int doadd) {
  int wv = threadIdx.x >> 6, lane = threadIdx.x & 63;
  int row = blockIdx.x * 4 + wv;
  size_t base = (size_t)row * DIM;
  float v[6];
  float ss = 0.f;
  if (doadd) {
#pragma unroll
    for (int j = 0; j < 6; j++) {
      int o = lane + 64 * j;
      v[j] = x[base + o] + p0[base + o] + p1[base + o];
      x[base + o] = v[j];
      ss += v[j] * v[j];
    }
  } else {
#pragma unroll
    for (int j = 0; j < 6; j++) { v[j] = x[base + lane + 64 * j]; ss += v[j] * v[j]; }
  }
#pragma unroll
  for (int m = 32; m; m >>= 1) ss += __shfl_xor(ss, m);
  float s = rsqrtf(ss * (1.0f / DIM) + 1e-6f);
#pragma unroll
  for (int j = 0; j < 6; j++)
    out[base + lane + 64 * j] = f2bf(v[j] * s * w[lane + 64 * j]);
}

// ---- unified 64x64 GEMM. KSTEP 32 or 64 (two [64][32] LDS subtiles, conflict-free stride).
// MODE 3: gelu->outb. MODE 4: qkv + fused rope (perm-pair shuffle) -> qb/kb/vtb.
// MODE 5: split-K fp32 partial. MODE 6: A staged from flash partials (fused amerge), mode-5 out.
template <int KSTEP, int MODE>
__global__ __launch_bounds__(256) void gemm64_kernel(const unsigned short* __restrict__ A,
                                                     const unsigned short* __restrict__ Wt,
                                                     const float* __restrict__ bias, int N, int K,
                                                     unsigned short* __restrict__ outb,
                                                     unsigned short* __restrict__ outb2,
                                                     unsigned short* __restrict__ outv,
                                                     float* __restrict__ outf0,
                                                     float* __restrict__ outf1,
                                                     const float* __restrict__ pO,
                                                     const float* __restrict__ pM,
                                                     const float* __restrict__ pL,
                                                     const float2* __restrict__ cs2) {
  __shared__ __align__(16) unsigned short As[64 * KSTEP];
  __shared__ __align__(16) unsigned short Bs[64 * KSTEP];
  int tid = threadIdx.x;
  int wv = tid >> 6, lane = tid & 63;
  int wm = wv >> 1, wn = wv & 1;
  int row0 = blockIdx.x * 64, col0 = blockIdx.y * 64;
  int q = lane >> 4, c = lane & 15;
  int kchunk = K / gridDim.z;
  int kb0 = blockIdx.z * kchunk;
  floatx4 acc[2][2] = {};
  int sr = tid >> 2, sk = (tid & 3) * 8;
  const unsigned short* Ag = A + (size_t)(row0 + sr) * K + kb0 + sk;
  const unsigned short* Bg = Wt + (size_t)(col0 + sr) * K + kb0 + sk;
  unsigned short* Asl = As + tid * 8;
  unsigned short* Bsl = Bs + tid * 8;
  for (int k0 = 0; k0 < kchunk; k0 += KSTEP) {
    if (MODE == 6) {
      // build A tile from flash partials: O = (pO0*e0 + pO1*e1) / (l0*e0 + l1*e1)
      int row = row0 + sr, b = row >> 11, l = row & 2047;
      int kc = kb0 + k0 + sk;
      int h = kc / 48, d0 = kc % 48;
      int rowg = (b * 8 + h) * SEQ + l;
      float m0 = pM[rowg], m1 = pM[NRG + rowg];
      float l0 = pL[rowg], l1 = pL[NRG + rowg];
      float M = fmaxf(m0, m1);
      float e0 = __expf(m0 - M), e1 = __expf(m1 - M);
      float inv = 1.0f / (l0 * e0 + l1 * e1);
      e0 *= inv;
      e1 *= inv;
      const float* P0 = pO + (size_t)rowg * 48 + d0;
      const float* P1 = pO + ((size_t)NRG + rowg) * 48 + d0;
      ushort8 av;
#pragma unroll
      for (int j = 0; j < 8; j++) av[j] = f2bf(P0[j] * e0 + P1[j] * e1);
      *(ushort8*)Asl = av;
      gl2lds16(Bg + k0, Bsl);
    } else if (KSTEP == 32) {
      gl2lds16(Ag + k0, Asl);
      gl2lds16(Bg + k0, Bsl);
    } else {
      gl2lds16(Ag + k0, Asl);
      gl2lds16(Ag + k0 + 32, Asl + 2048);
      gl2lds16(Bg + k0, Bsl);
      gl2lds16(Bg + k0 + 32, Bsl + 2048);
    }
    __syncthreads();
    if (KSTEP == 32 || MODE == 6) {
      bf16x8 a0 = ldb8(&As[(wm * 32 + c) * 32 + q * 8]);
      bf16x8 a1 = ldb8(&As[(wm * 32 + 16 + c) * 32 + q * 8]);
      bf16x8 b0 = ldb8(&Bs[(wn * 32 + c) * 32 + q * 8]);
      bf16x8 b1 = ldb8(&Bs[(wn * 32 + 16 + c) * 32 + q * 8]);
      acc[0][0] = MFMA(a0, b0, acc[0][0]);
      acc[0][1] = MFMA(a0, b1, acc[0][1]);
      acc[1][0] = MFMA(a1, b0, acc[1][0]);
      acc[1][1] = MFMA(a1, b1, acc[1][1]);
    } else {
      bf16x8 aA[2], aB[2], bA[2], bB[2];
#pragma unroll
      for (int mt = 0; mt < 2; mt++) {
        aA[mt] = ldb8(&As[(wm * 32 + mt * 16 + c) * 32 + q * 8]);
        aB[mt] = ldb8(&As[2048 + (wm * 32 + mt * 16 + c) * 32 + q * 8]);
      }
#pragma unroll
      for (int nt = 0; nt < 2; nt++) {
        bA[nt] = ldb8(&Bs[(wn * 32 + nt * 16 + c) * 32 + q * 8]);
        bB[nt] = ldb8(&Bs[2048 + (wn * 32 + nt * 16 + c) * 32 + q * 8]);
      }
#pragma unroll
      for (int mt = 0; mt < 2; mt++)
#pragma unroll
        for (int nt = 0; nt < 2; nt++) {
          acc[mt][nt] = MFMA(aA[mt], bA[nt], acc[mt][nt]);
          acc[mt][nt] = MFMA(aB[mt], bB[nt], acc[mt][nt]);
        }
    }
    __syncthreads();
  }
  if (MODE == 4 && col0 < 768) {  // q/k with fused rope (block-uniform branch)
    const int isq = (col0 < 384) ? 1 : 0;
    unsigned short* dst = isq ? outb : outb2;
    float sc = isq ? ATT_SCALE : 1.0f;
#pragma unroll
    for (int tm = 0; tm < 2; tm++)
#pragma unroll
      for (int tn = 0; tn < 2; tn++)
#pragma unroll
        for (int r = 0; r < 4; r++) {
          int rg = row0 + wm * 32 + tm * 16 + q * 4 + r;
          int cg = col0 + wn * 32 + tn * 16 + c;
          float v = acc[tm][tn][r] + bias[cg];
          float pv = __shfl_xor(v, 1);  // rope partner: adjacent permuted column
          int cl = isq ? cg : cg - 384;
          int h = cl / 48, s = cl % 48;
          int l = rg & 2047, b = rg >> 11;
          float2 cs = cs2[l * 24 + (s >> 1)];
          float o = v * cs.x + ((s & 1) ? pv * cs.y : -pv * cs.y);
          dst[(((size_t)(b * 8 + h)) * SEQ + l) * HDP + s] = f2bf(o * sc);
        }
    return;
  }
  float* outf = blockIdx.z ? outf1 : outf0;
  int addb = (blockIdx.z == 0);
#pragma unroll
  for (int tm = 0; tm < 2; tm++)
#pragma unroll
    for (int tn = 0; tn < 2; tn++)
#pragma unroll
      for (int r = 0; r < 4; r++) {
        int rg = row0 + wm * 32 + tm * 16 + q * 4 + r;
        int cg = col0 + wn * 32 + tn * 16 + c;
        float v = acc[tm][tn][r] + (addb ? bias[cg] : 0.f);
        if (MODE == 3) {
          float g = v * 0.5f * (1.0f + erff(v * 0.70710678f));
          outb[(size_t)rg * N + cg] = f2bf(g);
        } else if (MODE == 4) {  // v scatter (col0 >= 768)
          int j = cg - 768;
          int h = j / HD, hd = j % HD;
          int b = rg >> 11, l = rg & 2047;
          outv[(((size_t)b * NH + h) * HDP + hd) * SEQ + l] = f2bf(v);
        } else {  // MODE 5 / 6: fp32 split-K partial
          outf[(size_t)rg * N + cg] = v;
        }
      }
}

// ---- flash attention v7: dbuf K/V staging + 2-way K-split + fp32 partials ----
__global__ __launch_bounds__(256) void fattn_kernel(const unsigned short* __restrict__ qb,
                                                    const unsigned short* __restrict__ kb,
                                                    const unsigned short* __restrict__ vt,
                                                    float* __restrict__ pO,
                                                    float* __restrict__ pM,
                                                    float* __restrict__ pL) {
  __shared__ __align__(16) unsigned short Ks[2][64][72];
  __shared__ __align__(16) unsigned short Vs[2][48][72];
  __shared__ __align__(16) unsigned short Pt[4][16][64];
  int tid = threadIdx.x;
  int wv = tid >> 6, lane = tid & 63;
  int q = lane >> 4, c = lane & 15;
  int i = blockIdx.x;
  int bh = 2 * (i & 7) + ((i >> 3) & 1);
  int rest = i >> 4;
  int z = rest & 1;
  int q0 = (rest >> 1) * 64;
  int kstart = q0 & ~255;
  int n = (SEQ - kstart) >> 6;
  int n2 = (n + 1) >> 1;
  int it0 = z * n2;
  int it1 = z ? n : n2;
  const unsigned short* qbase = qb + (size_t)bh * SEQ * HDP;
  const unsigned short* kbase = kb + (size_t)bh * SEQ * HDP;
  const unsigned short* vbase = vt + (size_t)bh * HDP * SEQ;
  int myrow = q0 + wv * 16;
  bf16x8 a0 = ldb8(qbase + (size_t)(myrow + c) * HDP + q * 8);
  bf16x8 a1 = ldb8(qbase + (size_t)(myrow + c) * HDP + 32 + q * 8);
  floatx4 O[3] = {};
  float mr[4] = {-3e38f, -3e38f, -3e38f, -3e38f};
  float lr[4] = {0.f, 0.f, 0.f, 0.f};
  int srow = tid >> 2, sch = (tid & 3) * 16;
  ushort8 kA, kB, vA, vB;
  const unsigned short* kg0 = kbase + (size_t)srow * HDP + sch;
  const unsigned short* vg0 = vbase + (size_t)srow * SEQ + sch;
  {
    int k0 = kstart + it0 * 64;
    kA = *(const ushort8*)(kg0 + (size_t)k0 * HDP);
    kB = *(const ushort8*)(kg0 + (size_t)k0 * HDP + 8);
    if (srow < 48) {
      vA = *(const ushort8*)(vg0 + k0);
      vB = *(const ushort8*)(vg0 + k0 + 8);
    }
  }
  for (int it = it0; it < it1; ++it) {
    int buf = it & 1;
    *(ushort8*)(&Ks[buf][srow][sch]) = kA;
    *(ushort8*)(&Ks[buf][srow][sch + 8]) = kB;
    if (srow < 48) {
      *(ushort8*)(&Vs[buf][srow][sch]) = vA;
      *(ushort8*)(&Vs[buf][srow][sch + 8]) = vB;
    }
    if (it + 1 < it1) {
      int k0 = kstart + (it + 1) * 64;
      kA = *(const ushort8*)(kg0 + (size_t)k0 * HDP);
      kB = *(const ushort8*)(kg0 + (size_t)k0 * HDP + 8);
      if (srow < 48) {
        vA = *(const ushort8*)(vg0 + k0);
        vB = *(const ushort8*)(vg0 + k0 + 8);
      }
    }
    __syncthreads();
    floatx4 S[4];
#pragma unroll
    for (int t = 0; t < 4; t++) {
      bf16x8 b0 = ldb8(&Ks[buf][t * 16 + c][q * 8]);
      bf16x8 b1 = ldb8(&Ks[buf][t * 16 + c][32 + q * 8]);
      floatx4 zz = {};
      zz = MFMA(a0, b0, zz);
      S[t] = MFMA(a1, b1, zz);
    }
    float alpha[4];
#pragma unroll
    for (int r = 0; r < 4; r++) {
      float m0 = fmaxf(fmaxf(S[0][r], S[1][r]), fmaxf(S[2][r], S[3][r]));
#pragma unroll
      for (int msk = 1; msk < 16; msk <<= 1) m0 = fmaxf(m0, __shfl_xor(m0, msk, 16));
      float nm = fmaxf(mr[r], m0);
      alpha[r] = __expf(mr[r] - nm);
      mr[r] = nm;
      lr[r] *= alpha[r];
    }
#pragma unroll
    for (int t = 0; t < 4; t++)
#pragma unroll
      for (int r = 0; r < 4; r++) {
        float pv = __expf(S[t][r] - mr[r]);
        lr[r] += pv;
        Pt[wv][q * 4 + r][t * 16 + c] = f2bf(pv);
      }
#pragma unroll
    for (int f = 0; f < 3; f++)
#pragma unroll
      for (int r = 0; r < 4; r++) O[f][r] *= alpha[r];
    bf16x8 pa0 = ldb8(&Pt[wv][c][q * 8]);
    bf16x8 pa1 = ldb8(&Pt[wv][c][32 + q * 8]);
#pragma unroll
    for (int f = 0; f < 3; f++) {
      bf16x8 v0 = ldb8(&Vs[buf][f * 16 + c][q * 8]);
      bf16x8 v1 = ldb8(&Vs[buf][f * 16 + c][32 + q * 8]);
      O[f] = MFMA(pa0, v0, O[f]);
      O[f] = MFMA(pa1, v1, O[f]);
    }
  }
#pragma unroll
  for (int r = 0; r < 4; r++)
#pragma unroll
    for (int msk = 1; msk < 16; msk <<= 1) lr[r] += __shfl_xor(lr[r], msk, 16);
  size_t pbase = (size_t)z * NRG + (size_t)bh * SEQ + myrow;
#pragma unroll
  for (int r = 0; r < 4; r++) {
    int row = q * 4 + r;
    if (c == 0) {
      pM[pbase + row] = mr[r];
      pL[pbase + row] = lr[r];
    }
#pragma unroll
    for (int f = 0; f < 3; f++) pO[(pbase + row) * 48 + f * 16 + c] = O[f][r];
  }
}

// ---- stable argsort(-mask) ranks via block scan ----
__global__ __launch_bounds__(256) void rank_kernel(const int* __restrict__ mask,
                                                   int* __restrict__ dest) {
  __shared__ int wsum[4];
  int b = blockIdx.x, t = threadIdx.x;
  int lane = t & 63, wv = t >> 6;
  const int* mb = mask + b * SEQ;
  int base = t * 8;
  int v[8];
  int s = 0;
#pragma unroll
  for (int j = 0; j < 8; j++) { v[j] = mb[base + j]; s += v[j]; }
  int incl = s;
  for (int off = 1; off < 64; off <<= 1) {
    int n = __shfl_up(incl, off);
    if (lane >= off) incl += n;
  }
  if (lane == 63) wsum[wv] = incl;
  __syncthreads();
  int P = incl - s;
  for (int w = 0; w < wv; w++) P += wsum[w];
  int run = 0;
#pragma unroll
  for (int j = 0; j < 8; j++) {
    int ones = P + run;
    int l = base + j;
    dest[b * SEQ + l] = v[j] ? ones : 512 + (l - ones);
    run += v[j];
  }
}

// ---- final: x+p0+p1 -> decoded_full + scattered visible/masked ----
__global__ __launch_bounds__(256) void output_kernel(const float* __restrict__ x,
                                                     const float* __restrict__ p0,
                                                     const float* __restrict__ p1,
                                                     const int* __restrict__ dest,
                                                     float* __restrict__ out) {
  int idx = blockIdx.x * 256 + threadIdx.x;
  int row = idx / 96, c = idx % 96;
  size_t base_i = (size_t)row * DIM;
  float4 v = ((const float4*)(x + base_i))[c];
  float4 a = ((const float4*)(p0 + base_i))[c];
  float4 bb = ((const float4*)(p1 + base_i))[c];
  v.x += a.x + bb.x; v.y += a.y + bb.y; v.z += a.z + bb.z; v.w += a.w + bb.w;
  ((float4*)(out + base_i))[c] = v;
  int b = row >> 11;
  int d = dest[row];
  size_t base = (size_t)NB * SEQ * DIM;
  size_t o;
  if (d < 512) o = base + ((size_t)b * 512 + d) * DIM;
  else o = base + (size_t)NB * 512 * DIM + ((size_t)b * 1536 + (d - 512)) * DIM;
  ((float4*)(out + o))[c] = v;
}

extern "C" void kernel_launch(void* const* d_in, const int* in_sizes, int n_in,
                              void* d_out, int out_size, void* d_ws, size_t ws_size,
                              hipStream_t stream) {
  const float* vis = (const float*)d_in[0];
  const int* ids = (const int*)d_in[1];
  const int* mask = (const int*)d_in[2];
  const float* mask_token = (const float*)d_in[6];
  const float* ln_in_w = (const float*)d_in[7];
  const float* ln1_w = (const float*)d_in[8];
  const float* ln2_w = (const float*)d_in[9];
  const float* Wq = (const float*)d_in[10];
  const float* bq = (const float*)d_in[11];
  const float* Wk = (const float*)d_in[12];
  const float* bk = (const float*)d_in[13];
  const float* Wv = (const float*)d_in[14];
  const float* bv = (const float*)d_in[15];
  const float* Wo = (const float*)d_in[16];
  const float* bo = (const float*)d_in[17];
  const float* W1 = (const float*)d_in[18];
  const float* b1 = (const float*)d_in[19];
  const float* W2 = (const float*)d_in[20];
  const float* b2 = (const float*)d_in[21];

  char* p = (char*)d_ws;
  size_t off = 0;
  auto alloc = [&](size_t n) -> void* {
    off = (off + 255) & ~(size_t)255;
    void* r = p + off;
    off += n;
    return r;
  };
  unsigned short* wqkvT = (unsigned short*)alloc((size_t)NLAYER * 1152 * DIM * 2);
  unsigned short* woT = (unsigned short*)alloc((size_t)NLAYER * DIM * DIM * 2);
  unsigned short* w1T = (unsigned short*)alloc((size_t)NLAYER * DIM * FF * 2);
  unsigned short* w2T = (unsigned short*)alloc((size_t)NLAYER * DIM * FF * 2);
  float* bqkv = (float*)alloc((size_t)NLAYER * 1152 * 4);
  float2* cs2 = (float2*)alloc((size_t)SEQ * 24 * 8);
  float* x = (float*)alloc((size_t)NB * SEQ * DIM * 4);
  unsigned short* hdn = (unsigned short*)alloc((size_t)NB * SEQ * DIM * 2);
  unsigned short* qb = (unsigned short*)alloc((size_t)NB * NH * SEQ * HDP * 2);
  unsigned short* kb = (unsigned short*)alloc((size_t)NB * NH * SEQ * HDP * 2);
  unsigned short* vtb = (unsigned short*)alloc((size_t)NB * NH * SEQ * HDP * 2);
  unsigned short* a1 = (unsigned short*)alloc((size_t)NB * SEQ * FF * 2);
  float* pA0 = (float*)alloc((size_t)NB * SEQ * DIM * 4);
  float* pA1 = (float*)alloc((size_t)NB * SEQ * DIM * 4);
  float* pB0 = (float*)alloc((size_t)NB * SEQ * DIM * 4);
  float* pB1 = (float*)alloc((size_t)NB * SEQ * DIM * 4);
  float* pO = (float*)alloc((size_t)2 * NRG * 48 * 4);
  float* pM = (float*)alloc((size_t)2 * NRG * 4);
  float* pL = (float*)alloc((size_t)2 * NRG * 4);
  int* dest = (int*)alloc((size_t)NB * SEQ * 4);

  // zero head-dim pad [48,64) for q/k (contracted by score MFMAs); qb+kb contiguous.
  hipMemsetAsync(qb, 0, (size_t)2 * NB * NH * SEQ * HDP * 2, stream);

  dim3 tb(32, 8);
  wtrans_kernel<<<dim3(12, 12, 8), tb, 0, stream>>>(Wq, wqkvT, 384, 384, 147456, 442368, 1);
  wtrans_kernel<<<dim3(12, 12, 8), tb, 0, stream>>>(Wk, wqkvT + 147456, 384, 384, 147456, 442368, 1);
  wtrans_kernel<<<dim3(12, 12, 8), tb, 0, stream>>>(Wv, wqkvT + 294912, 384, 384, 147456, 442368, 0);
  wtrans_kernel<<<dim3(12, 12, 8), tb, 0, stream>>>(Wo, woT, 384, 384, 147456, 147456, 0);
  wtrans_kernel<<<dim3(48, 12, 8), tb, 0, stream>>>(W1, w1T, 384, 1536, 589824, 589824, 0);
  wtrans_kernel<<<dim3(12, 48, 8), tb, 0, stream>>>(W2, w2T, 1536, 384, 589824, 589824, 0);
  biascat_kernel<<<(NLAYER * 1152 + 255) / 256, 256, 0, stream>>>(bq, bk, bv, bqkv);
  ropetab_kernel<<<(SEQ * 24 + 255) / 256, 256, 0, stream>>>(cs2);
  gatherrms_kernel<<<NB * SEQ / 4, 256, 0, stream>>>(vis, ids, mask_token, ln_in_w, x);

  for (int i = 0; i < NLAYER; i++) {
    size_t wo = (size_t)i * DIM * DIM;
    size_t wf = (size_t)i * DIM * FF;
    rmsadd_kernel<<<NB * SEQ / 4, 256, 0, stream>>>(x, pB0, pB1, ln1_w + i * DIM, hdn, i > 0);
    gemm64_kernel<64, 4><<<dim3(64, 18, 1), 256, 0, stream>>>(
        hdn, wqkvT + (size_t)i * 442368, bqkv + i * 1152, 1152, DIM, qb, kb, vtb, nullptr, nullptr,
        nullptr, nullptr, nullptr, cs2);
    fattn_kernel<<<1024, 256, 0, stream>>>(qb, kb, vtb, pO, pM, pL);
    gemm64_kernel<32, 6><<<dim3(64, 6, 2), 256, 0, stream>>>(
        nullptr, woT + wo, bo + i * DIM, DIM, DIM, nullptr, nullptr, nullptr, pA0, pA1, pO, pM, pL,
        nullptr);
    rmsadd_kernel<<<NB * SEQ / 4, 256, 0, stream>>>(x, pA0, pA1, ln2_w + i * DIM, hdn, 1);
    gemm64_kernel<64, 3><<<dim3(64, 24, 1), 256, 0, stream>>>(
        hdn, w1T + wf, b1 + i * FF, FF, DIM, a1, nullptr, nullptr, nullptr, nullptr, nullptr,
        nullptr, nullptr, nullptr);
    gemm64_kernel<64, 5><<<dim3(64, 6, 2), 256, 0, stream>>>(
        a1, w2T + wf, b2 + i * DIM, DIM, FF, nullptr, nullptr, nullptr, pB0, pB1, nullptr, nullptr,
        nullptr, nullptr);
  }
  rank_kernel<<<NB, 256, 0, stream>>>(mask, dest);
  output_kernel<<<NB * SEQ * 96 / 256, 256, 0, stream>>>(x, pB0, pB1, dest, (float*)d_out);
}